// Round 2
// baseline (2044.844 us; speedup 1.0000x reference)
//
#include <hip/hip_runtime.h>
#include <hip/hip_bf16.h>

#define N_USER 100000
#define N_ITEM 200000
#define N_NODE 300000
#define LATDIM 64
#define E_INTER 4000000
#define E_SOC  2000000

#define NODE_ELEMS (N_NODE * LATDIM)   // 19,200,000
#define USER_ELEMS (N_USER * LATDIM)   // 6,400,000

// bucket radix for CSR build: bucket = row >> 6 (64 rows/bucket)
#define BSHIFT 6
#define IB_NB ((N_NODE + 63) >> 6)     // 4688
#define SB_NB ((N_USER + 63) >> 6)     // 1563

// ---------------------------------------------------------------------------
// workspace layout (bytes), all offsets 16B-aligned:
//   socA     bf16[USER_ELEMS]        @ 0            12,800,000
//   socB     bf16[USER_ELEMS]        @ 12,800,000   12,800,000
//   fused    bf16[5*NODE_ELEMS]      @ 25,600,000  192,000,000
//     (CSR-build phase only, aliased onto fused while it is still dead:
//        tmpI  u64[E_INTER]  @ FUSED_OFF             32,000,000
//        tmpS  u64[E_SOC]    @ FUSED_OFF+32,000,000  16,000,000 )
//   iPairs   u64 [E_INTER]           @ 217,600,000  32,000,000
//   sPairs   u64 [E_SOC]             @ 249,600,000  16,000,000
//   iRowPtr  i32 [N_NODE+1]          @ 265,600,000   1,200,004 (pad)
//   iBOff    i32 [IB_NB+1]           @ 266,800,128      18,756
//   iBCur    i32 [IB_NB]             @ 266,820,608      18,752
//   sRowPtr  i32 [N_USER+1]          @ 268,000,128     400,004 (pad)
//   sBOff    i32 [SB_NB+1]           @ 268,400,256       6,256
//   sBCur    i32 [SB_NB]             @ 268,408,448       6,252
//   bSums    i32 [512]               @ 268,800,256       2,048
// total 268,802,304 (unchanged, verified)
// inter f32 accumulator lives in d_out (76.8 MB, dead until final_kernel).
#define SOC_BYTES 12800000
#define FUSED_OFF 25600000
#define IPAIR_OFF 217600000
#define SPAIR_OFF 249600000
#define IRP_OFF   265600000
#define IBOFF_OFF 266800128
#define IBCUR_OFF 266820608
#define SRP_OFF   268000128
#define SBOFF_OFF 268400256
#define SBCUR_OFF 268408448
#define BSUM_OFF  268800256
#define WS_REQUIRED 268802304ull

#define SCAN_CHUNK 1024

// ---------------------------------------------------------------------------
__global__ __launch_bounds__(256) void fill_diag(float* __restrict__ o, int n,
                                                 float v) {
  int i = blockIdx.x * blockDim.x + threadIdx.x;
  if (i < n) o[i] = v;
}

__global__ __launch_bounds__(256) void zero_i32(int* __restrict__ p, int n) {
  int i = blockIdx.x * blockDim.x + threadIdx.x;
  if (i < n) p[i] = 0;
}

__global__ __launch_bounds__(256) void copy_i32(const int* __restrict__ s,
                                                int* __restrict__ d, int n) {
  int i = blockIdx.x * blockDim.x + threadIdx.x;
  if (i < n) d[i] = s[i];
}

// ---------------------------------------------------------------------------
// CSR build, stage 1: bucket histogram (LDS-aggregated, grid-stride)
// ---------------------------------------------------------------------------
__global__ __launch_bounds__(256) void bucket_hist(const int* __restrict__ rows,
                                                   int* __restrict__ bCnt,
                                                   int nE, int nB) {
  __shared__ int h[IB_NB];   // max bucket count (inter); soc uses prefix
  for (int i = threadIdx.x; i < nB; i += 256) h[i] = 0;
  __syncthreads();
  int stride = gridDim.x * 256;
  for (int e = blockIdx.x * 256 + threadIdx.x; e < nE; e += stride)
    atomicAdd(&h[rows[e] >> BSHIFT], 1);
  __syncthreads();
  for (int i = threadIdx.x; i < nB; i += 256) {
    int v = h[i];
    if (v) atomicAdd(&bCnt[i], v);
  }
}

// ---------------------------------------------------------------------------
// scan over bucket counts: pass1 per-chunk sums
// ---------------------------------------------------------------------------
__global__ __launch_bounds__(256) void scan_pass1(const int* __restrict__ cnt,
                                                  int* __restrict__ bSums,
                                                  int n) {
  __shared__ int sred[4];
  int b = blockIdx.x, t = threadIdx.x;
  int base = b * SCAN_CHUNK;
  int s = 0;
  #pragma unroll
  for (int i = 0; i < 4; i++) {
    int idx = base + t + i * 256;
    if (idx < n) s += cnt[idx];
  }
  #pragma unroll
  for (int sh = 32; sh > 0; sh >>= 1) s += __shfl_xor(s, sh, 64);
  if ((t & 63) == 0) sred[t >> 6] = s;
  __syncthreads();
  if (t == 0) bSums[b] = sred[0] + sred[1] + sred[2] + sred[3];
}

// pass2: single block, exclusive scan of bSums[0..B) in place (B <= 512)
__global__ __launch_bounds__(512) void scan_pass2(int* bSums, int B) {
  __shared__ int waveTot[8];
  int t = threadIdx.x;
  int lane = t & 63, w = t >> 6;
  int orig = (t < B) ? bSums[t] : 0;
  int v = orig;
  #pragma unroll
  for (int sh = 1; sh < 64; sh <<= 1) {
    int u = __shfl_up(v, sh, 64);
    if (lane >= sh) v += u;
  }
  if (lane == 63) waveTot[w] = v;
  __syncthreads();
  int waveOff = 0;
  #pragma unroll
  for (int i = 0; i < 8; i++)
    if (i < w) waveOff += waveTot[i];
  v += waveOff;
  if (t < B) bSums[t] = v - orig;  // exclusive
}

// pass3: per-chunk exclusive scan + chunk offset -> bOff; bOff[n]=total
__global__ __launch_bounds__(256) void scan_pass3(const int* __restrict__ cnt,
                                                  const int* __restrict__ bSums,
                                                  int* __restrict__ bOff,
                                                  int n, int total) {
  __shared__ int waveTot[4];
  int b = blockIdx.x, t = threadIdx.x;
  int idx0 = b * SCAN_CHUNK + t * 4;
  int e0 = (idx0 + 0 < n) ? cnt[idx0 + 0] : 0;
  int e1 = (idx0 + 1 < n) ? cnt[idx0 + 1] : 0;
  int e2 = (idx0 + 2 < n) ? cnt[idx0 + 2] : 0;
  int e3 = (idx0 + 3 < n) ? cnt[idx0 + 3] : 0;
  int tsum = e0 + e1 + e2 + e3;
  int lane = t & 63, w = t >> 6;
  int v = tsum;
  #pragma unroll
  for (int sh = 1; sh < 64; sh <<= 1) {
    int u = __shfl_up(v, sh, 64);
    if (lane >= sh) v += u;
  }
  if (lane == 63) waveTot[w] = v;
  __syncthreads();
  int waveOff = 0;
  #pragma unroll
  for (int i = 0; i < 4; i++)
    if (i < w) waveOff += waveTot[i];
  int p0 = (v - tsum) + waveOff + bSums[b];
  int p1 = p0 + e0;
  int p2 = p1 + e1;
  int p3 = p2 + e2;
  if (idx0 + 0 < n) bOff[idx0 + 0] = p0;
  if (idx0 + 1 < n) bOff[idx0 + 1] = p1;
  if (idx0 + 2 < n) bOff[idx0 + 2] = p2;
  if (idx0 + 3 < n) bOff[idx0 + 3] = p3;
  if (b == 0 && t == 0) bOff[n] = total;
}

// ---------------------------------------------------------------------------
// stage 2: bin edges into bucket-major order.
// pack: [63:32]=valbits  [31:6]=col (<2^26)  [5:0]=row&63
// Active write frontier = nB cache lines (~300 KB) -> L2-resident, no
// partial-line writeback amplification.
// ---------------------------------------------------------------------------
__global__ __launch_bounds__(256) void bin_kernel(
    const int* __restrict__ rows, const int* __restrict__ cols,
    const float* __restrict__ vals, int* bCur,
    unsigned long long* __restrict__ tmp, int nE) {
  int e = blockIdx.x * 256 + threadIdx.x;
  if (e >= nE) return;
  int r = rows[e];
  int p = atomicAdd(&bCur[r >> BSHIFT], 1);
  tmp[p] = ((unsigned long long)__float_as_uint(vals[e]) << 32) |
           ((unsigned long long)(unsigned int)cols[e] << 6) |
           (unsigned long long)(r & 63);
}

// ---------------------------------------------------------------------------
// stage 3: one workgroup per bucket. LDS-hist the 64 row-lows, LDS exclusive
// scan -> rowPtr (free!), then place each edge at its exact CSR slot.
// All global writes land inside the bucket's contiguous CSR window.
// ---------------------------------------------------------------------------
__global__ __launch_bounds__(256) void finalize_kernel(
    const unsigned long long* __restrict__ tmp,
    const int* __restrict__ bOff, int* __restrict__ rowPtr,
    unsigned long long* __restrict__ pairs, int nRows) {
  __shared__ int cur[64];
  int b = blockIdx.x;
  int t = threadIdx.x;
  int start = bOff[b];
  int end = bOff[b + 1];
  if (t < 64) cur[t] = 0;
  __syncthreads();
  for (int e = start + t; e < end; e += 256)
    atomicAdd(&cur[(int)(tmp[e] & 63ull)], 1);
  __syncthreads();
  if (t < 64) {
    int v = cur[t];
    int x = v;
    #pragma unroll
    for (int sh = 1; sh < 64; sh <<= 1) {
      int u = __shfl_up(x, sh, 64);
      if (t >= sh) x += u;
    }
    int excl = x - v;
    cur[t] = excl;
    int row = (b << BSHIFT) + t;
    if (row < nRows) rowPtr[row] = start + excl;
    if (b == 0 && t == 0) rowPtr[nRows] = bOff[(nRows + 63) >> BSHIFT];
  }
  __syncthreads();
  for (int e = start + t; e < end; e += 256) {
    unsigned long long pk = tmp[e];
    int rl = (int)(pk & 63ull);
    int p = start + atomicAdd(&cur[rl], 1);
    pairs[p] = (pk & 0xffffffff00000000ull) | ((pk >> 6) & 0x3ffffffull);
  }
}

// ---------------------------------------------------------------------------
// init: f32 inputs -> f32 inter buffer (ini, in d_out) and bf16 soc buffer
// ---------------------------------------------------------------------------
__global__ __launch_bounds__(256) void init_convert(
    const float* __restrict__ uE, const float* __restrict__ iE,
    float* __restrict__ inter, __hip_bfloat16* __restrict__ soc) {
  int idx = blockIdx.x * blockDim.x + threadIdx.x;
  if (idx >= NODE_ELEMS) return;
  if (idx < USER_ELEMS) {
    float v = uE[idx];
    soc[idx] = __float2bfloat16(v);
    inter[idx] = v;
  } else {
    inter[idx] = iE[idx - USER_ELEMS];
  }
}

// ---------------------------------------------------------------------------
// fuse: one wave per node row (unchanged)
// ---------------------------------------------------------------------------
__global__ __launch_bounds__(256) void fuse_kernel(
    const __hip_bfloat16* __restrict__ soc_cur,
    const float* __restrict__ inter_cur,
    const float* __restrict__ W_gate,   // (5,2,128)
    const float* __restrict__ b_gate,   // (5,2)
    int k, __hip_bfloat16* __restrict__ fused_k) {
  int g = blockIdx.x * blockDim.x + threadIdx.x;
  int row = g >> 6;
  int lane = g & 63;
  if (row >= N_NODE) return;
  int off = row * LATDIM + lane;

  if (row < N_USER) {
    float z = __bfloat162float(soc_cur[off]);
    float h = inter_cur[off];
    const float* wg = W_gate + k * 256;
    float p0 = z * wg[lane] + h * wg[64 + lane];
    float p1 = z * wg[128 + lane] + h * wg[192 + lane];
    #pragma unroll
    for (int s = 32; s > 0; s >>= 1) {
      p0 += __shfl_xor(p0, s, 64);
      p1 += __shfl_xor(p1, s, 64);
    }
    p0 += b_gate[k * 2 + 0];
    p1 += b_gate[k * 2 + 1];
    p0 = p0 >= 0.f ? p0 : 0.01f * p0;   // leaky_relu(0.01)
    p1 = p1 >= 0.f ? p1 : 0.01f * p1;
    float mx = fmaxf(p0, p1);
    float e0 = __expf(p0 - mx);
    float e1 = __expf(p1 - mx);
    float inv = 1.f / (e0 + e1);
    float o = z * (e0 * inv) + h * (e1 * inv);
    fused_k[off] = __float2bfloat16(o);
  } else {
    fused_k[off] = __float2bfloat16(inter_cur[off]);
  }
}

// ---------------------------------------------------------------------------
// pull-based SpMM: one wave per output row, lane = feature dim.
// ---------------------------------------------------------------------------
__global__ __launch_bounds__(256) void spmm_pull_f32(
    const int* __restrict__ rowPtr,
    const unsigned long long* __restrict__ pairs,
    const __hip_bfloat16* __restrict__ x, float* __restrict__ out, int nRows) {
  int g = blockIdx.x * blockDim.x + threadIdx.x;
  int row = __builtin_amdgcn_readfirstlane(g >> 6);
  int lane = g & 63;
  if (row >= nRows) return;
  int start = rowPtr[row];
  int end = rowPtr[row + 1];
  float acc = 0.f;
  int e = start;
  for (; e + 1 < end; e += 2) {
    unsigned long long pk0 = pairs[e];
    unsigned long long pk1 = pairs[e + 1];
    int c0 = (int)(unsigned int)(pk0 & 0xffffffffu);
    int c1 = (int)(unsigned int)(pk1 & 0xffffffffu);
    float x0 = __bfloat162float(x[c0 * LATDIM + lane]);
    float x1 = __bfloat162float(x[c1 * LATDIM + lane]);
    acc += __uint_as_float((unsigned int)(pk0 >> 32)) * x0;
    acc += __uint_as_float((unsigned int)(pk1 >> 32)) * x1;
  }
  if (e < end) {
    unsigned long long pk = pairs[e];
    int c = (int)(unsigned int)(pk & 0xffffffffu);
    acc += __uint_as_float((unsigned int)(pk >> 32)) *
           __bfloat162float(x[c * LATDIM + lane]);
  }
  out[row * LATDIM + lane] = acc;
}

__global__ __launch_bounds__(256) void spmm_pull_bf16(
    const int* __restrict__ rowPtr,
    const unsigned long long* __restrict__ pairs,
    const __hip_bfloat16* __restrict__ x, __hip_bfloat16* __restrict__ out,
    int nRows) {
  int g = blockIdx.x * blockDim.x + threadIdx.x;
  int row = __builtin_amdgcn_readfirstlane(g >> 6);
  int lane = g & 63;
  if (row >= nRows) return;
  int start = rowPtr[row];
  int end = rowPtr[row + 1];
  float acc = 0.f;
  int e = start;
  for (; e + 1 < end; e += 2) {
    unsigned long long pk0 = pairs[e];
    unsigned long long pk1 = pairs[e + 1];
    int c0 = (int)(unsigned int)(pk0 & 0xffffffffu);
    int c1 = (int)(unsigned int)(pk1 & 0xffffffffu);
    float x0 = __bfloat162float(x[c0 * LATDIM + lane]);
    float x1 = __bfloat162float(x[c1 * LATDIM + lane]);
    acc += __uint_as_float((unsigned int)(pk0 >> 32)) * x0;
    acc += __uint_as_float((unsigned int)(pk1 >> 32)) * x1;
  }
  if (e < end) {
    unsigned long long pk = pairs[e];
    int c = (int)(unsigned int)(pk & 0xffffffffu);
    acc += __uint_as_float((unsigned int)(pk >> 32)) *
           __bfloat162float(x[c * LATDIM + lane]);
  }
  out[row * LATDIM + lane] = __float2bfloat16(acc);
}

// ---------------------------------------------------------------------------
// final: per-row 5-way attention over the 5 fused layers (unchanged)
// ---------------------------------------------------------------------------
__global__ __launch_bounds__(256) void final_kernel(
    const __hip_bfloat16* __restrict__ fused,
    const float* __restrict__ WL1,     // (5,320)
    const float* __restrict__ bL1,     // (5,)
    const float* __restrict__ WL2,
    const float* __restrict__ bL2,
    float* __restrict__ out) {
  int g = blockIdx.x * blockDim.x + threadIdx.x;
  int row = g >> 6;
  int lane = g & 63;
  if (row >= N_NODE) return;

  float f[5];
  #pragma unroll
  for (int k = 0; k < 5; k++)
    f[k] = __bfloat162float(fused[(size_t)k * NODE_ELEMS + row * LATDIM + lane]);

  const float* WL = (row < N_USER) ? WL1 : WL2;
  const float* bL = (row < N_USER) ? bL1 : bL2;

  float p[5];
  #pragma unroll
  for (int j = 0; j < 5; j++) {
    float s = 0.f;
    #pragma unroll
    for (int k = 0; k < 5; k++)
      s += f[k] * WL[j * 320 + k * 64 + lane];
    p[j] = s;
  }
  #pragma unroll
  for (int s = 32; s > 0; s >>= 1) {
    #pragma unroll
    for (int j = 0; j < 5; j++) p[j] += __shfl_xor(p[j], s, 64);
  }
  float mx = -1e30f;
  #pragma unroll
  for (int j = 0; j < 5; j++) {
    p[j] += bL[j];
    p[j] = p[j] >= 0.f ? p[j] : 0.01f * p[j];
    mx = fmaxf(mx, p[j]);
  }
  float sum = 0.f;
  #pragma unroll
  for (int j = 0; j < 5; j++) {
    p[j] = __expf(p[j] - mx);
    sum += p[j];
  }
  float inv = 1.f / sum;
  float o = 0.f;
  #pragma unroll
  for (int j = 0; j < 5; j++) o += (p[j] * inv) * f[j];
  out[row * LATDIM + lane] = o;
}

// ---------------------------------------------------------------------------
extern "C" void kernel_launch(void* const* d_in, const int* in_sizes, int n_in,
                              void* d_out, int out_size, void* d_ws,
                              size_t ws_size, hipStream_t stream) {
  const float* uE     = (const float*)d_in[0];
  const float* iE     = (const float*)d_in[1];
  const float* W_gate = (const float*)d_in[2];
  const float* b_gate = (const float*)d_in[3];
  const float* WL1    = (const float*)d_in[4];
  const float* bL1    = (const float*)d_in[5];
  const float* WL2    = (const float*)d_in[6];
  const float* bL2    = (const float*)d_in[7];
  const int* inter_rows = (const int*)d_in[8];
  const int* inter_cols = (const int*)d_in[9];
  const float* inter_vals = (const float*)d_in[10];
  const int* soc_rows   = (const int*)d_in[11];
  const int* soc_cols   = (const int*)d_in[12];
  const float* soc_vals = (const float*)d_in[13];
  float* out = (float*)d_out;

  if (ws_size < WS_REQUIRED) {
    float v = (float)(ws_size / (1024ull * 1024ull));
    fill_diag<<<(out_size + 255) / 256, 256, 0, stream>>>(out, out_size, v);
    return;
  }

  char* ws = (char*)d_ws;
  __hip_bfloat16* socBuf[2] = {(__hip_bfloat16*)ws,
                               (__hip_bfloat16*)(ws + SOC_BYTES)};
  __hip_bfloat16* fused = (__hip_bfloat16*)(ws + FUSED_OFF);
  unsigned long long* tmpI = (unsigned long long*)(ws + FUSED_OFF);
  unsigned long long* tmpS = (unsigned long long*)(ws + FUSED_OFF + 32000000);
  unsigned long long* iPairs = (unsigned long long*)(ws + IPAIR_OFF);
  unsigned long long* sPairs = (unsigned long long*)(ws + SPAIR_OFF);
  int* iRowPtr = (int*)(ws + IRP_OFF);
  int* iBOff   = (int*)(ws + IBOFF_OFF);
  int* iBCur   = (int*)(ws + IBCUR_OFF);
  int* sRowPtr = (int*)(ws + SRP_OFF);
  int* sBOff   = (int*)(ws + SBOFF_OFF);
  int* sBCur   = (int*)(ws + SBCUR_OFF);
  int* bSums   = (int*)(ws + BSUM_OFF);
  float* interF32 = (float*)d_out;   // dead until final_kernel rewrites it

  // ---- CSR build: inter graph (bucket radix, write-local) ----
  int iChunks = (IB_NB + SCAN_CHUNK - 1) / SCAN_CHUNK;   // 5
  zero_i32<<<(IB_NB + 255) / 256, 256, 0, stream>>>(iBCur, IB_NB);
  bucket_hist<<<512, 256, 0, stream>>>(inter_rows, iBCur, E_INTER, IB_NB);
  scan_pass1<<<iChunks, 256, 0, stream>>>(iBCur, bSums, IB_NB);
  scan_pass2<<<1, 512, 0, stream>>>(bSums, iChunks);
  scan_pass3<<<iChunks, 256, 0, stream>>>(iBCur, bSums, iBOff, IB_NB, E_INTER);
  copy_i32<<<(IB_NB + 255) / 256, 256, 0, stream>>>(iBOff, iBCur, IB_NB);
  bin_kernel<<<(E_INTER + 255) / 256, 256, 0, stream>>>(
      inter_rows, inter_cols, inter_vals, iBCur, tmpI, E_INTER);
  finalize_kernel<<<IB_NB, 256, 0, stream>>>(tmpI, iBOff, iRowPtr, iPairs,
                                             N_NODE);

  // ---- CSR build: soc graph ----
  int sChunks = (SB_NB + SCAN_CHUNK - 1) / SCAN_CHUNK;   // 2
  zero_i32<<<(SB_NB + 255) / 256, 256, 0, stream>>>(sBCur, SB_NB);
  bucket_hist<<<512, 256, 0, stream>>>(soc_rows, sBCur, E_SOC, SB_NB);
  scan_pass1<<<sChunks, 256, 0, stream>>>(sBCur, bSums, SB_NB);
  scan_pass2<<<1, 512, 0, stream>>>(bSums, sChunks);
  scan_pass3<<<sChunks, 256, 0, stream>>>(sBCur, bSums, sBOff, SB_NB, E_SOC);
  copy_i32<<<(SB_NB + 255) / 256, 256, 0, stream>>>(sBOff, sBCur, SB_NB);
  bin_kernel<<<(E_SOC + 255) / 256, 256, 0, stream>>>(
      soc_rows, soc_cols, soc_vals, sBCur, tmpS, E_SOC);
  finalize_kernel<<<SB_NB, 256, 0, stream>>>(tmpS, sBOff, sRowPtr, sPairs,
                                             N_USER);

  // ---- main pipeline ----
  init_convert<<<NODE_ELEMS / 256, 256, 0, stream>>>(uE, iE, interF32,
                                                     socBuf[0]);

  for (int k = 0; k < 5; k++) {
    __hip_bfloat16* fk = fused + (size_t)k * NODE_ELEMS;
    fuse_kernel<<<NODE_ELEMS / 256, 256, 0, stream>>>(
        socBuf[k & 1], interF32, W_gate, b_gate, k, fk);
    if (k < 4) {
      spmm_pull_f32<<<NODE_ELEMS / 256, 256, 0, stream>>>(iRowPtr, iPairs, fk,
                                                          interF32, N_NODE);
      spmm_pull_bf16<<<USER_ELEMS / 256, 256, 0, stream>>>(
          sRowPtr, sPairs, socBuf[k & 1], socBuf[(k + 1) & 1], N_USER);
    }
  }

  final_kernel<<<NODE_ELEMS / 256, 256, 0, stream>>>(fused, WL1, bL1, WL2, bL2,
                                                     out);
}

// Round 3
// 1748.510 us; speedup vs baseline: 1.1695x; 1.1695x over previous
//
#include <hip/hip_runtime.h>
#include <hip/hip_bf16.h>

#define N_USER 100000
#define N_ITEM 200000
#define N_NODE 300000
#define LATDIM 64
#define E_INTER 4000000
#define E_SOC  2000000

#define NODE_ELEMS (N_NODE * LATDIM)   // 19,200,000
#define USER_ELEMS (N_USER * LATDIM)   // 6,400,000

// coarse-bucket radix for CSR build: bucket = row >> 11 (2048 rows/bucket)
// nB <= 256 always -> single-kernel scan, LDS hist fits one 256-entry array.
#define CB_SHIFT 11
#define CB_ROWS 2048
#define IB_NB ((N_NODE + CB_ROWS - 1) >> CB_SHIFT)   // 147
#define SB_NB ((N_USER + CB_ROWS - 1) >> CB_SHIFT)   // 49

#define BIN_PER_T 32
#define BIN_CHUNK (256 * BIN_PER_T)    // 8192 edges per block

// ---------------------------------------------------------------------------
// workspace layout (bytes), all offsets 16B-aligned:
//   socA     bf16[USER_ELEMS]        @ 0            12,800,000
//   socB     bf16[USER_ELEMS]        @ 12,800,000   12,800,000
//   fused    bf16[5*NODE_ELEMS]      @ 25,600,000  192,000,000
//     (CSR-build phase only, aliased onto fused while it is still dead:
//        tmpI  u64[E_INTER]  @ FUSED_OFF             32,000,000
//        tmpS  u64[E_SOC]    @ FUSED_OFF+32,000,000  16,000,000 )
//   iPairs   u64 [E_INTER]           @ 217,600,000  32,000,000
//   sPairs   u64 [E_SOC]             @ 249,600,000  16,000,000
//   iRowPtr  i32 [N_NODE+1]          @ 265,600,000   1,200,004 (pad)
//   iBOff    i32 [<=256+1]           @ 266,800,128       1,028
//   iBCur    i32 [<=256]             @ 266,820,608       1,024
//   sRowPtr  i32 [N_USER+1]          @ 268,000,128     400,004 (pad)
//   sBOff    i32 [<=256+1]           @ 268,400,256       1,028
//   sBCur    i32 [<=256]             @ 268,408,448       1,024
// total 268,802,304 (unchanged, verified)
// inter f32 accumulator lives in d_out (76.8 MB, dead until final_kernel).
#define SOC_BYTES 12800000
#define FUSED_OFF 25600000
#define IPAIR_OFF 217600000
#define SPAIR_OFF 249600000
#define IRP_OFF   265600000
#define IBOFF_OFF 266800128
#define IBCUR_OFF 266820608
#define SRP_OFF   268000128
#define SBOFF_OFF 268400256
#define SBCUR_OFF 268408448
#define WS_REQUIRED 268802304ull

// ---------------------------------------------------------------------------
__global__ __launch_bounds__(256) void fill_diag(float* __restrict__ o, int n,
                                                 float v) {
  int i = blockIdx.x * blockDim.x + threadIdx.x;
  if (i < n) o[i] = v;
}

__global__ __launch_bounds__(256) void zero_i32(int* __restrict__ p, int n) {
  int i = blockIdx.x * blockDim.x + threadIdx.x;
  if (i < n) p[i] = 0;
}

// ---------------------------------------------------------------------------
// CSR build, stage 1: coarse-bucket histogram (LDS-aggregated, grid-stride)
// ---------------------------------------------------------------------------
__global__ __launch_bounds__(256) void bucket_hist(const int* __restrict__ rows,
                                                   int* __restrict__ bCnt,
                                                   int nE, int nB) {
  __shared__ int h[256];
  h[threadIdx.x] = 0;
  __syncthreads();
  int stride = gridDim.x * 256;
  for (int e = blockIdx.x * 256 + threadIdx.x; e < nE; e += stride)
    atomicAdd(&h[rows[e] >> CB_SHIFT], 1);
  __syncthreads();
  if (threadIdx.x < nB) {
    int v = h[threadIdx.x];
    if (v) atomicAdd(&bCnt[threadIdx.x], v);
  }
}

// single-block exclusive scan over <=256 bucket counts.
// Writes bOff[0..n] and initializes the cursor array (may alias cnt).
__global__ __launch_bounds__(256) void scan_single(const int* __restrict__ cnt,
                                                   int* __restrict__ bOff,
                                                   int* __restrict__ bCur,
                                                   int n) {
  __shared__ int waveTot[4];
  int t = threadIdx.x;
  int lane = t & 63, w = t >> 6;
  int orig = (t < n) ? cnt[t] : 0;
  int v = orig;
  #pragma unroll
  for (int sh = 1; sh < 64; sh <<= 1) {
    int u = __shfl_up(v, sh, 64);
    if (lane >= sh) v += u;
  }
  if (lane == 63) waveTot[w] = v;
  __syncthreads();
  int woff = 0;
  #pragma unroll
  for (int i = 0; i < 4; i++)
    if (i < w) woff += waveTot[i];
  v += woff;
  int excl = v - orig;
  if (t < n) {
    bOff[t] = excl;
    bCur[t] = excl;
  }
  if (t == n - 1) bOff[n] = excl + orig;
}

// ---------------------------------------------------------------------------
// stage 2: block-aggregated binning into bucket-major order.
// Per block: LDS-count its 8192 edges over <=147 buckets, reserve one global
// run per bucket (ONE atomic per bucket per block), then scatter -- each
// block-bucket run is ~56 contiguous u64 (448 B), so writes are line-sized.
// pack: [63:32]=valbits  [31:11]=col (<2^19 so fits)  [10:0]=row&2047
// ---------------------------------------------------------------------------
__global__ __launch_bounds__(256) void bin_kernel(
    const int* __restrict__ rows, const int* __restrict__ cols,
    const float* __restrict__ vals, int* __restrict__ gCur,
    unsigned long long* __restrict__ tmp, int nE, int nB) {
  __shared__ int cnt[256];
  __shared__ int cur[256];
  int t = threadIdx.x;
  int base = blockIdx.x * BIN_CHUNK;
  cnt[t] = 0;
  __syncthreads();
  #pragma unroll 4
  for (int i = 0; i < BIN_PER_T; i++) {
    int e = base + t + i * 256;
    if (e < nE) atomicAdd(&cnt[rows[e] >> CB_SHIFT], 1);
  }
  __syncthreads();
  if (t < nB) {
    int c = cnt[t];
    cur[t] = c ? atomicAdd(&gCur[t], c) : 0;
  }
  __syncthreads();
  #pragma unroll 4
  for (int i = 0; i < BIN_PER_T; i++) {
    int e = base + t + i * 256;
    if (e < nE) {
      int r = rows[e];
      int p = atomicAdd(&cur[r >> CB_SHIFT], 1);
      tmp[p] = ((unsigned long long)__float_as_uint(vals[e]) << 32) |
               ((unsigned long long)(unsigned int)cols[e] << CB_SHIFT) |
               (unsigned long long)(r & (CB_ROWS - 1));
    }
  }
}

// ---------------------------------------------------------------------------
// stage 3: one workgroup per bucket (2048 rows). LDS-hist row-lows, LDS scan
// -> rowPtr for the bucket's rows (free), then place each edge at its exact
// CSR slot. The bucket's ~218 KB window is written by ONE block (one XCD):
// line-local, no cross-XCD thrash.
// ---------------------------------------------------------------------------
__global__ __launch_bounds__(256) void finalize_kernel(
    const unsigned long long* __restrict__ tmp,
    const int* __restrict__ bOff, int* __restrict__ rowPtr,
    unsigned long long* __restrict__ pairs, int nRows) {
  __shared__ int cur[CB_ROWS];   // 8 KB
  __shared__ int waveTot[4];
  int b = blockIdx.x, t = threadIdx.x;
  int start = bOff[b];
  int end = bOff[b + 1];
  for (int i = t; i < CB_ROWS; i += 256) cur[i] = 0;
  __syncthreads();
  for (int e = start + t; e < end; e += 256)
    atomicAdd(&cur[(int)(tmp[e] & (unsigned long long)(CB_ROWS - 1))], 1);
  __syncthreads();
  // exclusive scan of cur[0..2048): 8 sequential per thread + cross-thread
  int loc[8];
  int run = 0;
  int sbase = t * 8;
  #pragma unroll
  for (int i = 0; i < 8; i++) {
    loc[i] = run;
    run += cur[sbase + i];
  }
  int lane = t & 63, w = t >> 6;
  int v = run;
  #pragma unroll
  for (int sh = 1; sh < 64; sh <<= 1) {
    int u = __shfl_up(v, sh, 64);
    if (lane >= sh) v += u;
  }
  if (lane == 63) waveTot[w] = v;
  __syncthreads();
  int woff = 0;
  #pragma unroll
  for (int i = 0; i < 4; i++)
    if (i < w) woff += waveTot[i];
  int toff = (v - run) + woff;   // exclusive prefix for this thread's 8 slots
  __syncthreads();
  int rowBase = b << CB_SHIFT;
  #pragma unroll
  for (int i = 0; i < 8; i++) {
    int excl = toff + loc[i];
    cur[sbase + i] = excl;
    int row = rowBase + sbase + i;
    if (row < nRows) rowPtr[row] = start + excl;
  }
  if (b == 0 && t == 0) rowPtr[nRows] = bOff[gridDim.x];
  __syncthreads();
  for (int e = start + t; e < end; e += 256) {
    unsigned long long pk = tmp[e];
    int rl = (int)(pk & (unsigned long long)(CB_ROWS - 1));
    int p = start + atomicAdd(&cur[rl], 1);
    pairs[p] = (pk & 0xffffffff00000000ull) |
               ((pk >> CB_SHIFT) & 0x1fffffull);
  }
}

// ---------------------------------------------------------------------------
// init: f32 inputs -> f32 inter buffer (ini, in d_out) and bf16 soc buffer
// ---------------------------------------------------------------------------
__global__ __launch_bounds__(256) void init_convert(
    const float* __restrict__ uE, const float* __restrict__ iE,
    float* __restrict__ inter, __hip_bfloat16* __restrict__ soc) {
  int idx = blockIdx.x * blockDim.x + threadIdx.x;
  if (idx >= NODE_ELEMS) return;
  if (idx < USER_ELEMS) {
    float v = uE[idx];
    soc[idx] = __float2bfloat16(v);
    inter[idx] = v;
  } else {
    inter[idx] = iE[idx - USER_ELEMS];
  }
}

// ---------------------------------------------------------------------------
// fuse: one wave per node row (unchanged)
// ---------------------------------------------------------------------------
__global__ __launch_bounds__(256) void fuse_kernel(
    const __hip_bfloat16* __restrict__ soc_cur,
    const float* __restrict__ inter_cur,
    const float* __restrict__ W_gate,   // (5,2,128)
    const float* __restrict__ b_gate,   // (5,2)
    int k, __hip_bfloat16* __restrict__ fused_k) {
  int g = blockIdx.x * blockDim.x + threadIdx.x;
  int row = g >> 6;
  int lane = g & 63;
  if (row >= N_NODE) return;
  int off = row * LATDIM + lane;

  if (row < N_USER) {
    float z = __bfloat162float(soc_cur[off]);
    float h = inter_cur[off];
    const float* wg = W_gate + k * 256;
    float p0 = z * wg[lane] + h * wg[64 + lane];
    float p1 = z * wg[128 + lane] + h * wg[192 + lane];
    #pragma unroll
    for (int s = 32; s > 0; s >>= 1) {
      p0 += __shfl_xor(p0, s, 64);
      p1 += __shfl_xor(p1, s, 64);
    }
    p0 += b_gate[k * 2 + 0];
    p1 += b_gate[k * 2 + 1];
    p0 = p0 >= 0.f ? p0 : 0.01f * p0;   // leaky_relu(0.01)
    p1 = p1 >= 0.f ? p1 : 0.01f * p1;
    float mx = fmaxf(p0, p1);
    float e0 = __expf(p0 - mx);
    float e1 = __expf(p1 - mx);
    float inv = 1.f / (e0 + e1);
    float o = z * (e0 * inv) + h * (e1 * inv);
    fused_k[off] = __float2bfloat16(o);
  } else {
    fused_k[off] = __float2bfloat16(inter_cur[off]);
  }
}

// ---------------------------------------------------------------------------
// pull-based SpMM: one wave per output row, lane = feature dim.
// ---------------------------------------------------------------------------
__global__ __launch_bounds__(256) void spmm_pull_f32(
    const int* __restrict__ rowPtr,
    const unsigned long long* __restrict__ pairs,
    const __hip_bfloat16* __restrict__ x, float* __restrict__ out, int nRows) {
  int g = blockIdx.x * blockDim.x + threadIdx.x;
  int row = __builtin_amdgcn_readfirstlane(g >> 6);
  int lane = g & 63;
  if (row >= nRows) return;
  int start = rowPtr[row];
  int end = rowPtr[row + 1];
  float acc = 0.f;
  int e = start;
  for (; e + 1 < end; e += 2) {
    unsigned long long pk0 = pairs[e];
    unsigned long long pk1 = pairs[e + 1];
    int c0 = (int)(unsigned int)(pk0 & 0xffffffffu);
    int c1 = (int)(unsigned int)(pk1 & 0xffffffffu);
    float x0 = __bfloat162float(x[c0 * LATDIM + lane]);
    float x1 = __bfloat162float(x[c1 * LATDIM + lane]);
    acc += __uint_as_float((unsigned int)(pk0 >> 32)) * x0;
    acc += __uint_as_float((unsigned int)(pk1 >> 32)) * x1;
  }
  if (e < end) {
    unsigned long long pk = pairs[e];
    int c = (int)(unsigned int)(pk & 0xffffffffu);
    acc += __uint_as_float((unsigned int)(pk >> 32)) *
           __bfloat162float(x[c * LATDIM + lane]);
  }
  out[row * LATDIM + lane] = acc;
}

__global__ __launch_bounds__(256) void spmm_pull_bf16(
    const int* __restrict__ rowPtr,
    const unsigned long long* __restrict__ pairs,
    const __hip_bfloat16* __restrict__ x, __hip_bfloat16* __restrict__ out,
    int nRows) {
  int g = blockIdx.x * blockDim.x + threadIdx.x;
  int row = __builtin_amdgcn_readfirstlane(g >> 6);
  int lane = g & 63;
  if (row >= nRows) return;
  int start = rowPtr[row];
  int end = rowPtr[row + 1];
  float acc = 0.f;
  int e = start;
  for (; e + 1 < end; e += 2) {
    unsigned long long pk0 = pairs[e];
    unsigned long long pk1 = pairs[e + 1];
    int c0 = (int)(unsigned int)(pk0 & 0xffffffffu);
    int c1 = (int)(unsigned int)(pk1 & 0xffffffffu);
    float x0 = __bfloat162float(x[c0 * LATDIM + lane]);
    float x1 = __bfloat162float(x[c1 * LATDIM + lane]);
    acc += __uint_as_float((unsigned int)(pk0 >> 32)) * x0;
    acc += __uint_as_float((unsigned int)(pk1 >> 32)) * x1;
  }
  if (e < end) {
    unsigned long long pk = pairs[e];
    int c = (int)(unsigned int)(pk & 0xffffffffu);
    acc += __uint_as_float((unsigned int)(pk >> 32)) *
           __bfloat162float(x[c * LATDIM + lane]);
  }
  out[row * LATDIM + lane] = __float2bfloat16(acc);
}

// ---------------------------------------------------------------------------
// final: per-row 5-way attention over the 5 fused layers (unchanged)
// ---------------------------------------------------------------------------
__global__ __launch_bounds__(256) void final_kernel(
    const __hip_bfloat16* __restrict__ fused,
    const float* __restrict__ WL1,     // (5,320)
    const float* __restrict__ bL1,     // (5,)
    const float* __restrict__ WL2,
    const float* __restrict__ bL2,
    float* __restrict__ out) {
  int g = blockIdx.x * blockDim.x + threadIdx.x;
  int row = g >> 6;
  int lane = g & 63;
  if (row >= N_NODE) return;

  float f[5];
  #pragma unroll
  for (int k = 0; k < 5; k++)
    f[k] = __bfloat162float(fused[(size_t)k * NODE_ELEMS + row * LATDIM + lane]);

  const float* WL = (row < N_USER) ? WL1 : WL2;
  const float* bL = (row < N_USER) ? bL1 : bL2;

  float p[5];
  #pragma unroll
  for (int j = 0; j < 5; j++) {
    float s = 0.f;
    #pragma unroll
    for (int k = 0; k < 5; k++)
      s += f[k] * WL[j * 320 + k * 64 + lane];
    p[j] = s;
  }
  #pragma unroll
  for (int s = 32; s > 0; s >>= 1) {
    #pragma unroll
    for (int j = 0; j < 5; j++) p[j] += __shfl_xor(p[j], s, 64);
  }
  float mx = -1e30f;
  #pragma unroll
  for (int j = 0; j < 5; j++) {
    p[j] += bL[j];
    p[j] = p[j] >= 0.f ? p[j] : 0.01f * p[j];
    mx = fmaxf(mx, p[j]);
  }
  float sum = 0.f;
  #pragma unroll
  for (int j = 0; j < 5; j++) {
    p[j] = __expf(p[j] - mx);
    sum += p[j];
  }
  float inv = 1.f / sum;
  float o = 0.f;
  #pragma unroll
  for (int j = 0; j < 5; j++) o += (p[j] * inv) * f[j];
  out[row * LATDIM + lane] = o;
}

// ---------------------------------------------------------------------------
extern "C" void kernel_launch(void* const* d_in, const int* in_sizes, int n_in,
                              void* d_out, int out_size, void* d_ws,
                              size_t ws_size, hipStream_t stream) {
  const float* uE     = (const float*)d_in[0];
  const float* iE     = (const float*)d_in[1];
  const float* W_gate = (const float*)d_in[2];
  const float* b_gate = (const float*)d_in[3];
  const float* WL1    = (const float*)d_in[4];
  const float* bL1    = (const float*)d_in[5];
  const float* WL2    = (const float*)d_in[6];
  const float* bL2    = (const float*)d_in[7];
  const int* inter_rows = (const int*)d_in[8];
  const int* inter_cols = (const int*)d_in[9];
  const float* inter_vals = (const float*)d_in[10];
  const int* soc_rows   = (const int*)d_in[11];
  const int* soc_cols   = (const int*)d_in[12];
  const float* soc_vals = (const float*)d_in[13];
  float* out = (float*)d_out;

  if (ws_size < WS_REQUIRED) {
    float v = (float)(ws_size / (1024ull * 1024ull));
    fill_diag<<<(out_size + 255) / 256, 256, 0, stream>>>(out, out_size, v);
    return;
  }

  char* ws = (char*)d_ws;
  __hip_bfloat16* socBuf[2] = {(__hip_bfloat16*)ws,
                               (__hip_bfloat16*)(ws + SOC_BYTES)};
  __hip_bfloat16* fused = (__hip_bfloat16*)(ws + FUSED_OFF);
  unsigned long long* tmpI = (unsigned long long*)(ws + FUSED_OFF);
  unsigned long long* tmpS = (unsigned long long*)(ws + FUSED_OFF + 32000000);
  unsigned long long* iPairs = (unsigned long long*)(ws + IPAIR_OFF);
  unsigned long long* sPairs = (unsigned long long*)(ws + SPAIR_OFF);
  int* iRowPtr = (int*)(ws + IRP_OFF);
  int* iBOff   = (int*)(ws + IBOFF_OFF);
  int* iBCur   = (int*)(ws + IBCUR_OFF);
  int* sRowPtr = (int*)(ws + SRP_OFF);
  int* sBOff   = (int*)(ws + SBOFF_OFF);
  int* sBCur   = (int*)(ws + SBCUR_OFF);
  float* interF32 = (float*)d_out;   // dead until final_kernel rewrites it

  // ---- CSR build: inter graph (block-aggregated two-pass radix) ----
  zero_i32<<<1, 256, 0, stream>>>(iBCur, IB_NB);
  bucket_hist<<<512, 256, 0, stream>>>(inter_rows, iBCur, E_INTER, IB_NB);
  scan_single<<<1, 256, 0, stream>>>(iBCur, iBOff, iBCur, IB_NB);
  bin_kernel<<<(E_INTER + BIN_CHUNK - 1) / BIN_CHUNK, 256, 0, stream>>>(
      inter_rows, inter_cols, inter_vals, iBCur, tmpI, E_INTER, IB_NB);
  finalize_kernel<<<IB_NB, 256, 0, stream>>>(tmpI, iBOff, iRowPtr, iPairs,
                                             N_NODE);

  // ---- CSR build: soc graph ----
  zero_i32<<<1, 256, 0, stream>>>(sBCur, SB_NB);
  bucket_hist<<<512, 256, 0, stream>>>(soc_rows, sBCur, E_SOC, SB_NB);
  scan_single<<<1, 256, 0, stream>>>(sBCur, sBOff, sBCur, SB_NB);
  bin_kernel<<<(E_SOC + BIN_CHUNK - 1) / BIN_CHUNK, 256, 0, stream>>>(
      soc_rows, soc_cols, soc_vals, sBCur, tmpS, E_SOC, SB_NB);
  finalize_kernel<<<SB_NB, 256, 0, stream>>>(tmpS, sBOff, sRowPtr, sPairs,
                                             N_USER);

  // ---- main pipeline ----
  init_convert<<<NODE_ELEMS / 256, 256, 0, stream>>>(uE, iE, interF32,
                                                     socBuf[0]);

  for (int k = 0; k < 5; k++) {
    __hip_bfloat16* fk = fused + (size_t)k * NODE_ELEMS;
    fuse_kernel<<<NODE_ELEMS / 256, 256, 0, stream>>>(
        socBuf[k & 1], interF32, W_gate, b_gate, k, fk);
    if (k < 4) {
      spmm_pull_f32<<<NODE_ELEMS / 256, 256, 0, stream>>>(iRowPtr, iPairs, fk,
                                                          interF32, N_NODE);
      spmm_pull_bf16<<<USER_ELEMS / 256, 256, 0, stream>>>(
          sRowPtr, sPairs, socBuf[k & 1], socBuf[(k + 1) & 1], N_USER);
    }
  }

  final_kernel<<<NODE_ELEMS / 256, 256, 0, stream>>>(fused, WL1, bL1, WL2, bL2,
                                                     out);
}

// Round 5
// 1288.608 us; speedup vs baseline: 1.5869x; 1.3569x over previous
//
#include <hip/hip_runtime.h>
#include <hip/hip_bf16.h>

#define N_USER 100000
#define N_ITEM 200000
#define N_NODE 300000
#define LATDIM 64
#define E_INTER 4000000
#define E_SOC  2000000

#define NODE_ELEMS (N_NODE * LATDIM)   // 19,200,000
#define USER_ELEMS (N_USER * LATDIM)   // 6,400,000

// coarse-bucket radix for CSR build: bucket = row >> 11 (2048 rows/bucket)
#define CB_SHIFT 11
#define CB_ROWS 2048
#define IB_NB ((N_NODE + CB_ROWS - 1) >> CB_SHIFT)   // 147
#define SB_NB ((N_USER + CB_ROWS - 1) >> CB_SHIFT)   // 49

#define BIN_PER_T 32
#define BIN_CHUNK (256 * BIN_PER_T)    // 8192 edges per block

// ---------------------------------------------------------------------------
// workspace layout (bytes) -- unchanged from round 3 (verified):
//   socA     bf16[USER_ELEMS]        @ 0            12,800,000
//   socB     bf16[USER_ELEMS]        @ 12,800,000   12,800,000
//   fused    bf16[5*NODE_ELEMS]      @ 25,600,000  192,000,000
//     (CSR-build phase aliases tmpI/tmpS onto fused while it is dead)
//   iPairs   u64 [E_INTER]           @ 217,600,000  32,000,000
//   sPairs   u64 [E_SOC]             @ 249,600,000  16,000,000
//   iRowPtr  i32 [N_NODE+1]          @ 265,600,000
//   iBOff    i32 [<=256+1]           @ 266,800,128
//   iBCur    i32 [<=256]             @ 266,820,608
//   sRowPtr  i32 [N_USER+1]          @ 268,000,128
//   sBOff    i32 [<=256+1]           @ 268,400,256
//   sBCur    i32 [<=256]             @ 268,408,448
// total 268,802,304
// inter f32 accumulator lives in d_out (76.8 MB, dead until final_kernel).
#define SOC_BYTES 12800000
#define FUSED_OFF 25600000
#define IPAIR_OFF 217600000
#define SPAIR_OFF 249600000
#define IRP_OFF   265600000
#define IBOFF_OFF 266800128
#define IBCUR_OFF 266820608
#define SRP_OFF   268000128
#define SBOFF_OFF 268400256
#define SBCUR_OFF 268408448
#define WS_REQUIRED 268802304ull

// ---------------------------------------------------------------------------
__global__ __launch_bounds__(256) void fill_diag(float* __restrict__ o, int n,
                                                 float v) {
  int i = blockIdx.x * blockDim.x + threadIdx.x;
  if (i < n) o[i] = v;
}

__global__ __launch_bounds__(256) void zero_i32(int* __restrict__ p, int n) {
  int i = blockIdx.x * blockDim.x + threadIdx.x;
  if (i < n) p[i] = 0;
}

// ---------------------------------------------------------------------------
// CSR build, stage 1: coarse-bucket histogram (LDS-aggregated, grid-stride)
// ---------------------------------------------------------------------------
__global__ __launch_bounds__(256) void bucket_hist(const int* __restrict__ rows,
                                                   int* __restrict__ bCnt,
                                                   int nE, int nB) {
  __shared__ int h[256];
  h[threadIdx.x] = 0;
  __syncthreads();
  int stride = gridDim.x * 256;
  for (int e = blockIdx.x * 256 + threadIdx.x; e < nE; e += stride)
    atomicAdd(&h[rows[e] >> CB_SHIFT], 1);
  __syncthreads();
  if (threadIdx.x < nB) {
    int v = h[threadIdx.x];
    if (v) atomicAdd(&bCnt[threadIdx.x], v);
  }
}

// single-block exclusive scan over <=256 bucket counts.
__global__ __launch_bounds__(256) void scan_single(const int* __restrict__ cnt,
                                                   int* __restrict__ bOff,
                                                   int* __restrict__ bCur,
                                                   int n) {
  __shared__ int waveTot[4];
  int t = threadIdx.x;
  int lane = t & 63, w = t >> 6;
  int orig = (t < n) ? cnt[t] : 0;
  int v = orig;
  #pragma unroll
  for (int sh = 1; sh < 64; sh <<= 1) {
    int u = __shfl_up(v, sh, 64);
    if (lane >= sh) v += u;
  }
  if (lane == 63) waveTot[w] = v;
  __syncthreads();
  int woff = 0;
  #pragma unroll
  for (int i = 0; i < 4; i++)
    if (i < w) woff += waveTot[i];
  v += woff;
  int excl = v - orig;
  if (t < n) {
    bOff[t] = excl;
    bCur[t] = excl;
  }
  if (t == n - 1) bOff[n] = excl + orig;
}

// ---------------------------------------------------------------------------
// stage 2: block-aggregated binning into bucket-major order.
// pack: [63:32]=valbits  [31:11]=col  [10:0]=row&2047
// ---------------------------------------------------------------------------
__global__ __launch_bounds__(256) void bin_kernel(
    const int* __restrict__ rows, const int* __restrict__ cols,
    const float* __restrict__ vals, int* __restrict__ gCur,
    unsigned long long* __restrict__ tmp, int nE, int nB) {
  __shared__ int cnt[256];
  __shared__ int cur[256];
  int t = threadIdx.x;
  int base = blockIdx.x * BIN_CHUNK;
  cnt[t] = 0;
  __syncthreads();
  #pragma unroll 4
  for (int i = 0; i < BIN_PER_T; i++) {
    int e = base + t + i * 256;
    if (e < nE) atomicAdd(&cnt[rows[e] >> CB_SHIFT], 1);
  }
  __syncthreads();
  if (t < nB) {
    int c = cnt[t];
    cur[t] = c ? atomicAdd(&gCur[t], c) : 0;
  }
  __syncthreads();
  #pragma unroll 4
  for (int i = 0; i < BIN_PER_T; i++) {
    int e = base + t + i * 256;
    if (e < nE) {
      int r = rows[e];
      int p = atomicAdd(&cur[r >> CB_SHIFT], 1);
      tmp[p] = ((unsigned long long)__float_as_uint(vals[e]) << 32) |
               ((unsigned long long)(unsigned int)cols[e] << CB_SHIFT) |
               (unsigned long long)(r & (CB_ROWS - 1));
    }
  }
}

// ---------------------------------------------------------------------------
// stage 3: one workgroup per bucket (2048 rows). LDS-hist + scan -> rowPtr,
// then place each edge at its exact CSR slot (bucket window = one XCD).
// ---------------------------------------------------------------------------
__global__ __launch_bounds__(256) void finalize_kernel(
    const unsigned long long* __restrict__ tmp,
    const int* __restrict__ bOff, int* __restrict__ rowPtr,
    unsigned long long* __restrict__ pairs, int nRows) {
  __shared__ int cur[CB_ROWS];   // 8 KB
  __shared__ int waveTot[4];
  int b = blockIdx.x, t = threadIdx.x;
  int start = bOff[b];
  int end = bOff[b + 1];
  for (int i = t; i < CB_ROWS; i += 256) cur[i] = 0;
  __syncthreads();
  for (int e = start + t; e < end; e += 256)
    atomicAdd(&cur[(int)(tmp[e] & (unsigned long long)(CB_ROWS - 1))], 1);
  __syncthreads();
  int loc[8];
  int run = 0;
  int sbase = t * 8;
  #pragma unroll
  for (int i = 0; i < 8; i++) {
    loc[i] = run;
    run += cur[sbase + i];
  }
  int lane = t & 63, w = t >> 6;
  int v = run;
  #pragma unroll
  for (int sh = 1; sh < 64; sh <<= 1) {
    int u = __shfl_up(v, sh, 64);
    if (lane >= sh) v += u;
  }
  if (lane == 63) waveTot[w] = v;
  __syncthreads();
  int woff = 0;
  #pragma unroll
  for (int i = 0; i < 4; i++)
    if (i < w) woff += waveTot[i];
  int toff = (v - run) + woff;
  __syncthreads();
  int rowBase = b << CB_SHIFT;
  #pragma unroll
  for (int i = 0; i < 8; i++) {
    int excl = toff + loc[i];
    cur[sbase + i] = excl;
    int row = rowBase + sbase + i;
    if (row < nRows) rowPtr[row] = start + excl;
  }
  if (b == 0 && t == 0) rowPtr[nRows] = bOff[gridDim.x];
  __syncthreads();
  for (int e = start + t; e < end; e += 256) {
    unsigned long long pk = tmp[e];
    int rl = (int)(pk & (unsigned long long)(CB_ROWS - 1));
    int p = start + atomicAdd(&cur[rl], 1);
    pairs[p] = (pk & 0xffffffff00000000ull) |
               ((pk >> CB_SHIFT) & 0x1fffffull);
  }
}

// ---------------------------------------------------------------------------
// init: f32 inputs -> f32 inter (d_out), bf16 soc, and fused[0] item slice
// (item rows of fused[0] are just bf16(iE), so write them here once).
// ---------------------------------------------------------------------------
__global__ __launch_bounds__(256) void init_convert(
    const float* __restrict__ uE, const float* __restrict__ iE,
    float* __restrict__ inter, __hip_bfloat16* __restrict__ soc,
    __hip_bfloat16* __restrict__ fused0) {
  int idx = blockIdx.x * blockDim.x + threadIdx.x;
  if (idx >= NODE_ELEMS) return;
  if (idx < USER_ELEMS) {
    float v = uE[idx];
    soc[idx] = __float2bfloat16(v);
    inter[idx] = v;
  } else {
    float v = iE[idx - USER_ELEMS];
    inter[idx] = v;
    fused0[idx] = __float2bfloat16(v);
  }
}

// ---------------------------------------------------------------------------
// fuse: USER rows only (item slices of fused[k] are written by init/spmm).
// ---------------------------------------------------------------------------
__global__ __launch_bounds__(256) void fuse_kernel(
    const __hip_bfloat16* __restrict__ soc_cur,
    const float* __restrict__ inter_cur,
    const float* __restrict__ W_gate,   // (5,2,128)
    const float* __restrict__ b_gate,   // (5,2)
    int k, __hip_bfloat16* __restrict__ fused_k) {
  int g = blockIdx.x * blockDim.x + threadIdx.x;
  int row = g >> 6;
  int lane = g & 63;
  if (row >= N_USER) return;
  int off = row * LATDIM + lane;

  float z = __bfloat162float(soc_cur[off]);
  float h = inter_cur[off];
  const float* wg = W_gate + k * 256;
  float p0 = z * wg[lane] + h * wg[64 + lane];
  float p1 = z * wg[128 + lane] + h * wg[192 + lane];
  #pragma unroll
  for (int s = 32; s > 0; s >>= 1) {
    p0 += __shfl_xor(p0, s, 64);
    p1 += __shfl_xor(p1, s, 64);
  }
  p0 += b_gate[k * 2 + 0];
  p1 += b_gate[k * 2 + 1];
  p0 = p0 >= 0.f ? p0 : 0.01f * p0;   // leaky_relu(0.01)
  p1 = p1 >= 0.f ? p1 : 0.01f * p1;
  float mx = fmaxf(p0, p1);
  float e0 = __expf(p0 - mx);
  float e1 = __expf(p1 - mx);
  float inv = 1.f / (e0 + e1);
  float o = z * (e0 * inv) + h * (e1 * inv);
  fused_k[off] = __float2bfloat16(o);
}

// ---------------------------------------------------------------------------
// pull-SpMM row accumulator: 8-wide unrolled gather (4 acc chains) for MLP.
// Main loop: 8 contiguous pair loads + 8 independent gathers in flight.
// Epilogue: predicated 8-wide, wave-uniform selects (clamped index re-reads
// the last pair; val zeroed -> no contribution).
// ---------------------------------------------------------------------------
__device__ __forceinline__ float row_accum(
    const int* __restrict__ rowPtr,
    const unsigned long long* __restrict__ pairs,
    const __hip_bfloat16* __restrict__ x, int row, int lane) {
  int start = rowPtr[row];
  int end = rowPtr[row + 1];
  float a0 = 0.f, a1 = 0.f, a2 = 0.f, a3 = 0.f;
  int e = start;
  for (; e + 8 <= end; e += 8) {
    unsigned long long pk[8];
    #pragma unroll
    for (int i = 0; i < 8; i++) pk[i] = pairs[e + i];
    float xv[8];
    #pragma unroll
    for (int i = 0; i < 8; i++) {
      int c = (int)(unsigned int)(pk[i] & 0xffffffffu);
      xv[i] = __bfloat162float(x[c * LATDIM + lane]);
    }
    a0 += __uint_as_float((unsigned int)(pk[0] >> 32)) * xv[0];
    a1 += __uint_as_float((unsigned int)(pk[1] >> 32)) * xv[1];
    a2 += __uint_as_float((unsigned int)(pk[2] >> 32)) * xv[2];
    a3 += __uint_as_float((unsigned int)(pk[3] >> 32)) * xv[3];
    a0 += __uint_as_float((unsigned int)(pk[4] >> 32)) * xv[4];
    a1 += __uint_as_float((unsigned int)(pk[5] >> 32)) * xv[5];
    a2 += __uint_as_float((unsigned int)(pk[6] >> 32)) * xv[6];
    a3 += __uint_as_float((unsigned int)(pk[7] >> 32)) * xv[7];
  }
  if (e < end) {
    int last = end - 1;
    unsigned long long pk[8];
    unsigned int vb[8];
    #pragma unroll
    for (int i = 0; i < 8; i++) {
      int ei = e + i;
      int ec = ei < last ? ei : last;          // wave-uniform select
      pk[i] = pairs[ec];
      vb[i] = (ei < end) ? (unsigned int)(pk[i] >> 32) : 0u;
    }
    float xv[8];
    #pragma unroll
    for (int i = 0; i < 8; i++) {
      int c = (int)(unsigned int)(pk[i] & 0xffffffffu);
      xv[i] = __bfloat162float(x[c * LATDIM + lane]);
    }
    a0 += __uint_as_float(vb[0]) * xv[0];
    a1 += __uint_as_float(vb[1]) * xv[1];
    a2 += __uint_as_float(vb[2]) * xv[2];
    a3 += __uint_as_float(vb[3]) * xv[3];
    a0 += __uint_as_float(vb[4]) * xv[4];
    a1 += __uint_as_float(vb[5]) * xv[5];
    a2 += __uint_as_float(vb[6]) * xv[6];
    a3 += __uint_as_float(vb[7]) * xv[7];
  }
  return (a0 + a1) + (a2 + a3);
}

// ---------------------------------------------------------------------------
// dual SpMM: waves [0,N_NODE) = inter graph (f32 out + bf16 item slice of
// fused[k+1]); waves [N_NODE, N_NODE+N_USER) = soc graph (bf16 out).
// One dispatch overlaps both gathers.
// ---------------------------------------------------------------------------
__global__ __launch_bounds__(256) void spmm_dual(
    const int* __restrict__ iRowPtr,
    const unsigned long long* __restrict__ iPairs,
    const __hip_bfloat16* __restrict__ xI, float* __restrict__ outI,
    __hip_bfloat16* __restrict__ fusedNext,
    const int* __restrict__ sRowPtr,
    const unsigned long long* __restrict__ sPairs,
    const __hip_bfloat16* __restrict__ xS,
    __hip_bfloat16* __restrict__ outS) {
  int g = blockIdx.x * 256 + threadIdx.x;
  int wave = __builtin_amdgcn_readfirstlane(g >> 6);
  int lane = g & 63;
  if (wave < N_NODE) {
    float acc = row_accum(iRowPtr, iPairs, xI, wave, lane);
    int off = wave * LATDIM + lane;
    outI[off] = acc;
    if (wave >= N_USER) fusedNext[off] = __float2bfloat16(acc);
  } else {
    int r = wave - N_NODE;
    if (r < N_USER) {
      float acc = row_accum(sRowPtr, sPairs, xS, r, lane);
      outS[r * LATDIM + lane] = __float2bfloat16(acc);
    }
  }
}

// ---------------------------------------------------------------------------
// final: per-row 5-way attention over the 5 fused layers (unchanged)
// ---------------------------------------------------------------------------
__global__ __launch_bounds__(256) void final_kernel(
    const __hip_bfloat16* __restrict__ fused,
    const float* __restrict__ WL1,     // (5,320)
    const float* __restrict__ bL1,     // (5,)
    const float* __restrict__ WL2,
    const float* __restrict__ bL2,
    float* __restrict__ out) {
  int g = blockIdx.x * blockDim.x + threadIdx.x;
  int row = g >> 6;
  int lane = g & 63;
  if (row >= N_NODE) return;

  float f[5];
  #pragma unroll
  for (int k = 0; k < 5; k++)
    f[k] = __bfloat162float(fused[(size_t)k * NODE_ELEMS + row * LATDIM + lane]);

  const float* WL = (row < N_USER) ? WL1 : WL2;
  const float* bL = (row < N_USER) ? bL1 : bL2;

  float p[5];
  #pragma unroll
  for (int j = 0; j < 5; j++) {
    float s = 0.f;
    #pragma unroll
    for (int k = 0; k < 5; k++)
      s += f[k] * WL[j * 320 + k * 64 + lane];
    p[j] = s;
  }
  #pragma unroll
  for (int s = 32; s > 0; s >>= 1) {
    #pragma unroll
    for (int j = 0; j < 5; j++) p[j] += __shfl_xor(p[j], s, 64);
  }
  float mx = -1e30f;
  #pragma unroll
  for (int j = 0; j < 5; j++) {
    p[j] += bL[j];
    p[j] = p[j] >= 0.f ? p[j] : 0.01f * p[j];
    mx = fmaxf(mx, p[j]);
  }
  float sum = 0.f;
  #pragma unroll
  for (int j = 0; j < 5; j++) {
    p[j] = __expf(p[j] - mx);
    sum += p[j];
  }
  float inv = 1.f / sum;
  float o = 0.f;
  #pragma unroll
  for (int j = 0; j < 5; j++) o += (p[j] * inv) * f[j];
  out[row * LATDIM + lane] = o;
}

// ---------------------------------------------------------------------------
extern "C" void kernel_launch(void* const* d_in, const int* in_sizes, int n_in,
                              void* d_out, int out_size, void* d_ws,
                              size_t ws_size, hipStream_t stream) {
  const float* uE     = (const float*)d_in[0];
  const float* iE     = (const float*)d_in[1];
  const float* W_gate = (const float*)d_in[2];
  const float* b_gate = (const float*)d_in[3];
  const float* WL1    = (const float*)d_in[4];
  const float* bL1    = (const float*)d_in[5];
  const float* WL2    = (const float*)d_in[6];
  const float* bL2    = (const float*)d_in[7];
  const int* inter_rows = (const int*)d_in[8];
  const int* inter_cols = (const int*)d_in[9];
  const float* inter_vals = (const float*)d_in[10];
  const int* soc_rows   = (const int*)d_in[11];
  const int* soc_cols   = (const int*)d_in[12];
  const float* soc_vals = (const float*)d_in[13];
  float* out = (float*)d_out;

  if (ws_size < WS_REQUIRED) {
    float v = (float)(ws_size / (1024ull * 1024ull));
    fill_diag<<<(out_size + 255) / 256, 256, 0, stream>>>(out, out_size, v);
    return;
  }

  char* ws = (char*)d_ws;
  __hip_bfloat16* socBuf[2] = {(__hip_bfloat16*)ws,
                               (__hip_bfloat16*)(ws + SOC_BYTES)};
  __hip_bfloat16* fused = (__hip_bfloat16*)(ws + FUSED_OFF);
  unsigned long long* tmpI = (unsigned long long*)(ws + FUSED_OFF);
  unsigned long long* tmpS = (unsigned long long*)(ws + FUSED_OFF + 32000000);
  unsigned long long* iPairs = (unsigned long long*)(ws + IPAIR_OFF);
  unsigned long long* sPairs = (unsigned long long*)(ws + SPAIR_OFF);
  int* iRowPtr = (int*)(ws + IRP_OFF);
  int* iBOff   = (int*)(ws + IBOFF_OFF);
  int* iBCur   = (int*)(ws + IBCUR_OFF);
  int* sRowPtr = (int*)(ws + SRP_OFF);
  int* sBOff   = (int*)(ws + SBOFF_OFF);
  int* sBCur   = (int*)(ws + SBCUR_OFF);
  float* interF32 = (float*)d_out;   // dead until final_kernel rewrites it

  // ---- CSR build: inter graph (block-aggregated two-pass radix) ----
  zero_i32<<<1, 256, 0, stream>>>(iBCur, IB_NB);
  bucket_hist<<<512, 256, 0, stream>>>(inter_rows, iBCur, E_INTER, IB_NB);
  scan_single<<<1, 256, 0, stream>>>(iBCur, iBOff, iBCur, IB_NB);
  bin_kernel<<<(E_INTER + BIN_CHUNK - 1) / BIN_CHUNK, 256, 0, stream>>>(
      inter_rows, inter_cols, inter_vals, iBCur, tmpI, E_INTER, IB_NB);
  finalize_kernel<<<IB_NB, 256, 0, stream>>>(tmpI, iBOff, iRowPtr, iPairs,
                                             N_NODE);

  // ---- CSR build: soc graph ----
  zero_i32<<<1, 256, 0, stream>>>(sBCur, SB_NB);
  bucket_hist<<<512, 256, 0, stream>>>(soc_rows, sBCur, E_SOC, SB_NB);
  scan_single<<<1, 256, 0, stream>>>(sBCur, sBOff, sBCur, SB_NB);
  bin_kernel<<<(E_SOC + BIN_CHUNK - 1) / BIN_CHUNK, 256, 0, stream>>>(
      soc_rows, soc_cols, soc_vals, sBCur, tmpS, E_SOC, SB_NB);
  finalize_kernel<<<SB_NB, 256, 0, stream>>>(tmpS, sBOff, sRowPtr, sPairs,
                                             N_USER);

  // ---- main pipeline ----
  init_convert<<<NODE_ELEMS / 256, 256, 0, stream>>>(uE, iE, interF32,
                                                     socBuf[0], fused);

  for (int k = 0; k < 5; k++) {
    __hip_bfloat16* fk = fused + (size_t)k * NODE_ELEMS;
    fuse_kernel<<<USER_ELEMS / 256, 256, 0, stream>>>(
        socBuf[k & 1], interF32, W_gate, b_gate, k, fk);
    if (k < 4) {
      __hip_bfloat16* fnext = fk + NODE_ELEMS;
      spmm_dual<<<(NODE_ELEMS + USER_ELEMS) / 256, 256, 0, stream>>>(
          iRowPtr, iPairs, fk, interF32, fnext,
          sRowPtr, sPairs, socBuf[k & 1], socBuf[(k + 1) & 1]);
    }
  }

  final_kernel<<<NODE_ELEMS / 256, 256, 0, stream>>>(fused, WL1, bL1, WL2, bL2,
                                                     out);
}

// Round 6
// 1209.483 us; speedup vs baseline: 1.6907x; 1.0654x over previous
//
#include <hip/hip_runtime.h>
#include <hip/hip_bf16.h>

#define N_USER 100000
#define N_ITEM 200000
#define N_NODE 300000
#define LATDIM 64
#define E_INTER 4000000
#define E_SOC  2000000

#define NODE_ELEMS (N_NODE * LATDIM)   // 19,200,000
#define USER_ELEMS (N_USER * LATDIM)   // 6,400,000

// coarse-bucket radix for CSR build: bucket = row >> 9 (512 rows/bucket).
// Smaller buckets than round 5 (was 2048) -> finalize grid 147 -> 586 blocks
// (occupancy was the finalize bottleneck: 0.57 blocks/CU).
#define CB_SHIFT 9
#define CB_ROWS 512
#define IB_NB ((N_NODE + CB_ROWS - 1) >> CB_SHIFT)   // 586
#define SB_NB ((N_USER + CB_ROWS - 1) >> CB_SHIFT)   // 196
#define NB_MAX 640

#define BIN_PER_T 32
#define BIN_CHUNK (256 * BIN_PER_T)    // 8192 edges per block

// ---------------------------------------------------------------------------
// workspace layout (bytes) -- all within the verified 268,802,304 budget:
//   socA     bf16[USER_ELEMS]        @ 0            12,800,000
//   socB     bf16[USER_ELEMS]        @ 12,800,000   12,800,000
//   fused    bf16[5*NODE_ELEMS]      @ 25,600,000  192,000,000
//     (CSR-build phase aliases tmpI/tmpS onto fused while it is dead)
//   iPairs   u64 [E_INTER]           @ 217,600,000  32,000,000
//   sPairs   u64 [E_SOC]             @ 249,600,000  16,000,000
//   iRowPtr  i32 [N_NODE+1]          @ 265,600,000   1,200,004
//   iBOff    i32 [<=640+1]           @ 266,800,128       2,564
//   iBCur    i32 [<=640]             @ 266,802,688       2,560
//   sRowPtr  i32 [N_USER+1]          @ 268,000,128     400,004
//   sBOff    i32 [<=640+1]           @ 268,400,256       2,564
//   sBCur    i32 [<=640]             @ 268,402,816       2,560
// total <= 268,405,376
// inter f32 accumulator lives in d_out (76.8 MB, dead until final_kernel);
// only its USER slice is ever read (fuse_kernel), item slice is dead.
#define SOC_BYTES 12800000
#define FUSED_OFF 25600000
#define IPAIR_OFF 217600000
#define SPAIR_OFF 249600000
#define IRP_OFF   265600000
#define IBOFF_OFF 266800128
#define IBCUR_OFF 266802688
#define SRP_OFF   268000128
#define SBOFF_OFF 268400256
#define SBCUR_OFF 268402816
#define WS_REQUIRED 268802304ull

// ---------------------------------------------------------------------------
__global__ __launch_bounds__(256) void fill_diag(float* __restrict__ o, int n,
                                                 float v) {
  int i = blockIdx.x * blockDim.x + threadIdx.x;
  if (i < n) o[i] = v;
}

__global__ __launch_bounds__(256) void zero_i32(int* __restrict__ p, int n) {
  int i = blockIdx.x * blockDim.x + threadIdx.x;
  if (i < n) p[i] = 0;
}

// ---------------------------------------------------------------------------
// CSR build, stage 1: coarse-bucket histogram (LDS-aggregated, grid-stride)
// ---------------------------------------------------------------------------
__global__ __launch_bounds__(256) void bucket_hist(const int* __restrict__ rows,
                                                   int* __restrict__ bCnt,
                                                   int nE, int nB) {
  __shared__ int h[NB_MAX];
  for (int i = threadIdx.x; i < nB; i += 256) h[i] = 0;
  __syncthreads();
  int stride = gridDim.x * 256;
  for (int e = blockIdx.x * 256 + threadIdx.x; e < nE; e += stride)
    atomicAdd(&h[rows[e] >> CB_SHIFT], 1);
  __syncthreads();
  for (int i = threadIdx.x; i < nB; i += 256) {
    int v = h[i];
    if (v) atomicAdd(&bCnt[i], v);
  }
}

// single 1024-thread block: exclusive scan over n <= 1024 bucket counts.
// Writes bOff[0..n] and initializes the cursor array.
__global__ __launch_bounds__(1024) void scan_single(const int* __restrict__ cnt,
                                                    int* __restrict__ bOff,
                                                    int* __restrict__ bCur,
                                                    int n) {
  __shared__ int waveTot[16];
  int t = threadIdx.x;
  int lane = t & 63, w = t >> 6;
  int orig = (t < n) ? cnt[t] : 0;
  int v = orig;
  #pragma unroll
  for (int sh = 1; sh < 64; sh <<= 1) {
    int u = __shfl_up(v, sh, 64);
    if (lane >= sh) v += u;
  }
  if (lane == 63) waveTot[w] = v;
  __syncthreads();
  int woff = 0;
  #pragma unroll
  for (int i = 0; i < 16; i++)
    if (i < w) woff += waveTot[i];
  v += woff;
  int excl = v - orig;
  if (t < n) {
    bOff[t] = excl;
    bCur[t] = excl;
  }
  if (t == n - 1) bOff[n] = excl + orig;
}

// ---------------------------------------------------------------------------
// stage 2: block-aggregated binning into bucket-major order.
// pack: [63:32]=valbits  [31:9]=col (19 bits, fits)  [8:0]=row&511
// One global atomic per (block,bucket) -> each run is contiguous (line-sized
// writes); per-edge atomics stay in LDS.
// ---------------------------------------------------------------------------
__global__ __launch_bounds__(256) void bin_kernel(
    const int* __restrict__ rows, const int* __restrict__ cols,
    const float* __restrict__ vals, int* __restrict__ gCur,
    unsigned long long* __restrict__ tmp, int nE, int nB) {
  __shared__ int cnt[NB_MAX];
  __shared__ int cur[NB_MAX];
  int t = threadIdx.x;
  int base = blockIdx.x * BIN_CHUNK;
  for (int i = t; i < nB; i += 256) cnt[i] = 0;
  __syncthreads();
  #pragma unroll 4
  for (int i = 0; i < BIN_PER_T; i++) {
    int e = base + t + i * 256;
    if (e < nE) atomicAdd(&cnt[rows[e] >> CB_SHIFT], 1);
  }
  __syncthreads();
  for (int i = t; i < nB; i += 256) {
    int c = cnt[i];
    cur[i] = c ? atomicAdd(&gCur[i], c) : 0;
  }
  __syncthreads();
  #pragma unroll 4
  for (int i = 0; i < BIN_PER_T; i++) {
    int e = base + t + i * 256;
    if (e < nE) {
      int r = rows[e];
      int p = atomicAdd(&cur[r >> CB_SHIFT], 1);
      tmp[p] = ((unsigned long long)__float_as_uint(vals[e]) << 32) |
               ((unsigned long long)(unsigned int)cols[e] << CB_SHIFT) |
               (unsigned long long)(r & (CB_ROWS - 1));
    }
  }
}

// ---------------------------------------------------------------------------
// stage 3: one workgroup per bucket (512 rows, ~6.8K edges). LDS-hist +
// LDS scan -> rowPtr (free), then place each edge at its exact CSR slot.
// ---------------------------------------------------------------------------
__global__ __launch_bounds__(256) void finalize_kernel(
    const unsigned long long* __restrict__ tmp,
    const int* __restrict__ bOff, int* __restrict__ rowPtr,
    unsigned long long* __restrict__ pairs, int nRows) {
  __shared__ int cur[CB_ROWS];   // 2 KB
  __shared__ int waveTot[4];
  int b = blockIdx.x, t = threadIdx.x;
  int start = bOff[b];
  int end = bOff[b + 1];
  for (int i = t; i < CB_ROWS; i += 256) cur[i] = 0;
  __syncthreads();
  for (int e = start + t; e < end; e += 256)
    atomicAdd(&cur[(int)(tmp[e] & (unsigned long long)(CB_ROWS - 1))], 1);
  __syncthreads();
  // exclusive scan of cur[0..512): 2 sequential per thread + cross-thread
  int loc0, loc1;
  int sbase = t * 2;
  loc0 = 0;
  int run = cur[sbase];
  loc1 = run;
  run += cur[sbase + 1];
  int lane = t & 63, w = t >> 6;
  int v = run;
  #pragma unroll
  for (int sh = 1; sh < 64; sh <<= 1) {
    int u = __shfl_up(v, sh, 64);
    if (lane >= sh) v += u;
  }
  if (lane == 63) waveTot[w] = v;
  __syncthreads();
  int woff = 0;
  #pragma unroll
  for (int i = 0; i < 4; i++)
    if (i < w) woff += waveTot[i];
  int toff = (v - run) + woff;
  __syncthreads();
  int rowBase = b << CB_SHIFT;
  {
    int e0 = toff + loc0;
    int e1 = toff + loc1;
    cur[sbase] = e0;
    cur[sbase + 1] = e1;
    int r0 = rowBase + sbase;
    if (r0 < nRows) rowPtr[r0] = start + e0;
    if (r0 + 1 < nRows) rowPtr[r0 + 1] = start + e1;
  }
  if (b == 0 && t == 0) rowPtr[nRows] = bOff[gridDim.x];
  __syncthreads();
  for (int e = start + t; e < end; e += 256) {
    unsigned long long pk = tmp[e];
    int rl = (int)(pk & (unsigned long long)(CB_ROWS - 1));
    int p = start + atomicAdd(&cur[rl], 1);
    pairs[p] = (pk & 0xffffffff00000000ull) |
               ((pk >> CB_SHIFT) & 0x7fffffull);
  }
}

// ---------------------------------------------------------------------------
// init: f32 inputs -> f32 inter (d_out), bf16 soc, and fused[0] item slice
// ---------------------------------------------------------------------------
__global__ __launch_bounds__(256) void init_convert(
    const float* __restrict__ uE, const float* __restrict__ iE,
    float* __restrict__ inter, __hip_bfloat16* __restrict__ soc,
    __hip_bfloat16* __restrict__ fused0) {
  int idx = blockIdx.x * blockDim.x + threadIdx.x;
  if (idx >= NODE_ELEMS) return;
  if (idx < USER_ELEMS) {
    float v = uE[idx];
    soc[idx] = __float2bfloat16(v);
    inter[idx] = v;
  } else {
    float v = iE[idx - USER_ELEMS];
    inter[idx] = v;
    fused0[idx] = __float2bfloat16(v);
  }
}

// ---------------------------------------------------------------------------
// fuse: USER rows only (item slices of fused[k] are written by init/spmm).
// ---------------------------------------------------------------------------
__global__ __launch_bounds__(256) void fuse_kernel(
    const __hip_bfloat16* __restrict__ soc_cur,
    const float* __restrict__ inter_cur,
    const float* __restrict__ W_gate,   // (5,2,128)
    const float* __restrict__ b_gate,   // (5,2)
    int k, __hip_bfloat16* __restrict__ fused_k) {
  int g = blockIdx.x * blockDim.x + threadIdx.x;
  int row = g >> 6;
  int lane = g & 63;
  if (row >= N_USER) return;
  int off = row * LATDIM + lane;

  float z = __bfloat162float(soc_cur[off]);
  float h = inter_cur[off];
  const float* wg = W_gate + k * 256;
  float p0 = z * wg[lane] + h * wg[64 + lane];
  float p1 = z * wg[128 + lane] + h * wg[192 + lane];
  #pragma unroll
  for (int s = 32; s > 0; s >>= 1) {
    p0 += __shfl_xor(p0, s, 64);
    p1 += __shfl_xor(p1, s, 64);
  }
  p0 += b_gate[k * 2 + 0];
  p1 += b_gate[k * 2 + 1];
  p0 = p0 >= 0.f ? p0 : 0.01f * p0;   // leaky_relu(0.01)
  p1 = p1 >= 0.f ? p1 : 0.01f * p1;
  float mx = fmaxf(p0, p1);
  float e0 = __expf(p0 - mx);
  float e1 = __expf(p1 - mx);
  float inv = 1.f / (e0 + e1);
  float o = z * (e0 * inv) + h * (e1 * inv);
  fused_k[off] = __float2bfloat16(o);
}

// ---------------------------------------------------------------------------
// pull-SpMM row accumulator: 8-wide unrolled gather (4 acc chains) for MLP.
// ---------------------------------------------------------------------------
__device__ __forceinline__ float row_accum(
    const int* __restrict__ rowPtr,
    const unsigned long long* __restrict__ pairs,
    const __hip_bfloat16* __restrict__ x, int row, int lane) {
  int start = rowPtr[row];
  int end = rowPtr[row + 1];
  float a0 = 0.f, a1 = 0.f, a2 = 0.f, a3 = 0.f;
  int e = start;
  for (; e + 8 <= end; e += 8) {
    unsigned long long pk[8];
    #pragma unroll
    for (int i = 0; i < 8; i++) pk[i] = pairs[e + i];
    float xv[8];
    #pragma unroll
    for (int i = 0; i < 8; i++) {
      int c = (int)(unsigned int)(pk[i] & 0xffffffffu);
      xv[i] = __bfloat162float(x[c * LATDIM + lane]);
    }
    a0 += __uint_as_float((unsigned int)(pk[0] >> 32)) * xv[0];
    a1 += __uint_as_float((unsigned int)(pk[1] >> 32)) * xv[1];
    a2 += __uint_as_float((unsigned int)(pk[2] >> 32)) * xv[2];
    a3 += __uint_as_float((unsigned int)(pk[3] >> 32)) * xv[3];
    a0 += __uint_as_float((unsigned int)(pk[4] >> 32)) * xv[4];
    a1 += __uint_as_float((unsigned int)(pk[5] >> 32)) * xv[5];
    a2 += __uint_as_float((unsigned int)(pk[6] >> 32)) * xv[6];
    a3 += __uint_as_float((unsigned int)(pk[7] >> 32)) * xv[7];
  }
  if (e < end) {
    int last = end - 1;
    unsigned long long pk[8];
    unsigned int vb[8];
    #pragma unroll
    for (int i = 0; i < 8; i++) {
      int ei = e + i;
      int ec = ei < last ? ei : last;          // wave-uniform select
      pk[i] = pairs[ec];
      vb[i] = (ei < end) ? (unsigned int)(pk[i] >> 32) : 0u;
    }
    float xv[8];
    #pragma unroll
    for (int i = 0; i < 8; i++) {
      int c = (int)(unsigned int)(pk[i] & 0xffffffffu);
      xv[i] = __bfloat162float(x[c * LATDIM + lane]);
    }
    a0 += __uint_as_float(vb[0]) * xv[0];
    a1 += __uint_as_float(vb[1]) * xv[1];
    a2 += __uint_as_float(vb[2]) * xv[2];
    a3 += __uint_as_float(vb[3]) * xv[3];
    a0 += __uint_as_float(vb[4]) * xv[4];
    a1 += __uint_as_float(vb[5]) * xv[5];
    a2 += __uint_as_float(vb[6]) * xv[6];
    a3 += __uint_as_float(vb[7]) * xv[7];
  }
  return (a0 + a1) + (a2 + a3);
}

// ---------------------------------------------------------------------------
// dual SpMM: waves [0,N_NODE) = inter graph; waves [N_NODE,+N_USER) = soc.
// USER inter rows -> f32 outI (read by fuse); ITEM rows -> bf16 item slice
// of fused[k+1] ONLY (the f32 item accumulator is dead -> skip 51 MB write).
// ---------------------------------------------------------------------------
__global__ __launch_bounds__(256) void spmm_dual(
    const int* __restrict__ iRowPtr,
    const unsigned long long* __restrict__ iPairs,
    const __hip_bfloat16* __restrict__ xI, float* __restrict__ outI,
    __hip_bfloat16* __restrict__ fusedNext,
    const int* __restrict__ sRowPtr,
    const unsigned long long* __restrict__ sPairs,
    const __hip_bfloat16* __restrict__ xS,
    __hip_bfloat16* __restrict__ outS) {
  int g = blockIdx.x * 256 + threadIdx.x;
  int wave = __builtin_amdgcn_readfirstlane(g >> 6);
  int lane = g & 63;
  if (wave < N_NODE) {
    float acc = row_accum(iRowPtr, iPairs, xI, wave, lane);
    int off = wave * LATDIM + lane;
    if (wave < N_USER) outI[off] = acc;
    else fusedNext[off] = __float2bfloat16(acc);
  } else {
    int r = wave - N_NODE;
    if (r < N_USER) {
      float acc = row_accum(sRowPtr, sPairs, xS, r, lane);
      outS[r * LATDIM + lane] = __float2bfloat16(acc);
    }
  }
}

// ---------------------------------------------------------------------------
// final: per-row 5-way attention over the 5 fused layers (unchanged)
// ---------------------------------------------------------------------------
__global__ __launch_bounds__(256) void final_kernel(
    const __hip_bfloat16* __restrict__ fused,
    const float* __restrict__ WL1,     // (5,320)
    const float* __restrict__ bL1,     // (5,)
    const float* __restrict__ WL2,
    const float* __restrict__ bL2,
    float* __restrict__ out) {
  int g = blockIdx.x * blockDim.x + threadIdx.x;
  int row = g >> 6;
  int lane = g & 63;
  if (row >= N_NODE) return;

  float f[5];
  #pragma unroll
  for (int k = 0; k < 5; k++)
    f[k] = __bfloat162float(fused[(size_t)k * NODE_ELEMS + row * LATDIM + lane]);

  const float* WL = (row < N_USER) ? WL1 : WL2;
  const float* bL = (row < N_USER) ? bL1 : bL2;

  float p[5];
  #pragma unroll
  for (int j = 0; j < 5; j++) {
    float s = 0.f;
    #pragma unroll
    for (int k = 0; k < 5; k++)
      s += f[k] * WL[j * 320 + k * 64 + lane];
    p[j] = s;
  }
  #pragma unroll
  for (int s = 32; s > 0; s >>= 1) {
    #pragma unroll
    for (int j = 0; j < 5; j++) p[j] += __shfl_xor(p[j], s, 64);
  }
  float mx = -1e30f;
  #pragma unroll
  for (int j = 0; j < 5; j++) {
    p[j] += bL[j];
    p[j] = p[j] >= 0.f ? p[j] : 0.01f * p[j];
    mx = fmaxf(mx, p[j]);
  }
  float sum = 0.f;
  #pragma unroll
  for (int j = 0; j < 5; j++) {
    p[j] = __expf(p[j] - mx);
    sum += p[j];
  }
  float inv = 1.f / sum;
  float o = 0.f;
  #pragma unroll
  for (int j = 0; j < 5; j++) o += (p[j] * inv) * f[j];
  out[row * LATDIM + lane] = o;
}

// ---------------------------------------------------------------------------
extern "C" void kernel_launch(void* const* d_in, const int* in_sizes, int n_in,
                              void* d_out, int out_size, void* d_ws,
                              size_t ws_size, hipStream_t stream) {
  const float* uE     = (const float*)d_in[0];
  const float* iE     = (const float*)d_in[1];
  const float* W_gate = (const float*)d_in[2];
  const float* b_gate = (const float*)d_in[3];
  const float* WL1    = (const float*)d_in[4];
  const float* bL1    = (const float*)d_in[5];
  const float* WL2    = (const float*)d_in[6];
  const float* bL2    = (const float*)d_in[7];
  const int* inter_rows = (const int*)d_in[8];
  const int* inter_cols = (const int*)d_in[9];
  const float* inter_vals = (const float*)d_in[10];
  const int* soc_rows   = (const int*)d_in[11];
  const int* soc_cols   = (const int*)d_in[12];
  const float* soc_vals = (const float*)d_in[13];
  float* out = (float*)d_out;

  if (ws_size < WS_REQUIRED) {
    float v = (float)(ws_size / (1024ull * 1024ull));
    fill_diag<<<(out_size + 255) / 256, 256, 0, stream>>>(out, out_size, v);
    return;
  }

  char* ws = (char*)d_ws;
  __hip_bfloat16* socBuf[2] = {(__hip_bfloat16*)ws,
                               (__hip_bfloat16*)(ws + SOC_BYTES)};
  __hip_bfloat16* fused = (__hip_bfloat16*)(ws + FUSED_OFF);
  unsigned long long* tmpI = (unsigned long long*)(ws + FUSED_OFF);
  unsigned long long* tmpS = (unsigned long long*)(ws + FUSED_OFF + 32000000);
  unsigned long long* iPairs = (unsigned long long*)(ws + IPAIR_OFF);
  unsigned long long* sPairs = (unsigned long long*)(ws + SPAIR_OFF);
  int* iRowPtr = (int*)(ws + IRP_OFF);
  int* iBOff   = (int*)(ws + IBOFF_OFF);
  int* iBCur   = (int*)(ws + IBCUR_OFF);
  int* sRowPtr = (int*)(ws + SRP_OFF);
  int* sBOff   = (int*)(ws + SBOFF_OFF);
  int* sBCur   = (int*)(ws + SBCUR_OFF);
  float* interF32 = (float*)d_out;   // dead until final_kernel rewrites it

  // ---- CSR build: inter graph (block-aggregated two-pass radix) ----
  zero_i32<<<(IB_NB + 255) / 256, 256, 0, stream>>>(iBCur, IB_NB);
  bucket_hist<<<512, 256, 0, stream>>>(inter_rows, iBCur, E_INTER, IB_NB);
  scan_single<<<1, 1024, 0, stream>>>(iBCur, iBOff, iBCur, IB_NB);
  bin_kernel<<<(E_INTER + BIN_CHUNK - 1) / BIN_CHUNK, 256, 0, stream>>>(
      inter_rows, inter_cols, inter_vals, iBCur, tmpI, E_INTER, IB_NB);
  finalize_kernel<<<IB_NB, 256, 0, stream>>>(tmpI, iBOff, iRowPtr, iPairs,
                                             N_NODE);

  // ---- CSR build: soc graph ----
  zero_i32<<<(SB_NB + 255) / 256, 256, 0, stream>>>(sBCur, SB_NB);
  bucket_hist<<<512, 256, 0, stream>>>(soc_rows, sBCur, E_SOC, SB_NB);
  scan_single<<<1, 1024, 0, stream>>>(sBCur, sBOff, sBCur, SB_NB);
  bin_kernel<<<(E_SOC + BIN_CHUNK - 1) / BIN_CHUNK, 256, 0, stream>>>(
      soc_rows, soc_cols, soc_vals, sBCur, tmpS, E_SOC, SB_NB);
  finalize_kernel<<<SB_NB, 256, 0, stream>>>(tmpS, sBOff, sRowPtr, sPairs,
                                             N_USER);

  // ---- main pipeline ----
  init_convert<<<NODE_ELEMS / 256, 256, 0, stream>>>(uE, iE, interF32,
                                                     socBuf[0], fused);

  for (int k = 0; k < 5; k++) {
    __hip_bfloat16* fk = fused + (size_t)k * NODE_ELEMS;
    fuse_kernel<<<USER_ELEMS / 256, 256, 0, stream>>>(
        socBuf[k & 1], interF32, W_gate, b_gate, k, fk);
    if (k < 4) {
      __hip_bfloat16* fnext = fk + NODE_ELEMS;
      spmm_dual<<<(NODE_ELEMS + USER_ELEMS) / 256, 256, 0, stream>>>(
          iRowPtr, iPairs, fk, interF32, fnext,
          sRowPtr, sPairs, socBuf[k & 1], socBuf[(k + 1) & 1]);
    }
  }

  final_kernel<<<NODE_ELEMS / 256, 256, 0, stream>>>(fused, WL1, bL1, WL2, bL2,
                                                     out);
}

// Round 7
// 1059.706 us; speedup vs baseline: 1.9296x; 1.1413x over previous
//
#include <hip/hip_runtime.h>
#include <hip/hip_bf16.h>

#define N_USER 100000
#define N_ITEM 200000
#define N_NODE 300000
#define LATDIM 64
#define E_INTER 4000000
#define E_SOC  2000000

#define NODE_ELEMS (N_NODE * LATDIM)   // 19,200,000
#define USER_ELEMS (N_USER * LATDIM)   // 6,400,000

// coarse-bucket radix for CSR build: bucket = row >> 9 (512 rows/bucket)
#define CB_SHIFT 9
#define CB_ROWS 512
#define IB_NB ((N_NODE + CB_ROWS - 1) >> CB_SHIFT)   // 586
#define SB_NB ((N_USER + CB_ROWS - 1) >> CB_SHIFT)   // 196
#define NB_MAX 640

#define BIN_PER_T 32
#define BIN_CHUNK (256 * BIN_PER_T)    // 8192 edges per block
#define NBI_CHUNKS ((E_INTER + BIN_CHUNK - 1) / BIN_CHUNK)   // 489
#define NBS_CHUNKS ((E_SOC + BIN_CHUNK - 1) / BIN_CHUNK)     // 245

// ---------------------------------------------------------------------------
// workspace layout (bytes) -- within the verified 268,802,304 budget:
//   socA     bf16[USER_ELEMS]        @ 0            12,800,000
//   socB     bf16[USER_ELEMS]        @ 12,800,000   12,800,000
//   fused    bf16[5*NODE_ELEMS]      @ 25,600,000  192,000,000
//     (CSR-build phase aliases tmpI/tmpS onto fused while it is dead)
//   iPairs   u64 [E_INTER]           @ 217,600,000  32,000,000
//   sPairs   u64 [E_SOC]             @ 249,600,000  16,000,000
//   iRowPtr  i32 [N_NODE+1]          @ 265,600,000   1,200,004
//   iBOff    i32 [<=640+1]           @ 266,800,128
//   iBCur    i32 [<=640]             @ 266,802,688
//   sRowPtr  i32 [N_USER+1]          @ 268,000,128
//   sBOff    i32 [<=640+1]           @ 268,400,256
//   sBCur    i32 [<=640]             @ 268,402,816
// d_out is untouched until final_kernel (no more f32 inter scratch).
#define SOC_BYTES 12800000
#define FUSED_OFF 25600000
#define IPAIR_OFF 217600000
#define SPAIR_OFF 249600000
#define IRP_OFF   265600000
#define IBOFF_OFF 266800128
#define IBCUR_OFF 266802688
#define SRP_OFF   268000128
#define SBOFF_OFF 268400256
#define SBCUR_OFF 268402816
#define WS_REQUIRED 268802304ull

// ---------------------------------------------------------------------------
__global__ __launch_bounds__(256) void fill_diag(float* __restrict__ o, int n,
                                                 float v) {
  int i = blockIdx.x * blockDim.x + threadIdx.x;
  if (i < n) o[i] = v;
}

// zero both cursor arrays in one tiny launch
__global__ __launch_bounds__(1024) void zero_dual(int* __restrict__ a, int na,
                                                  int* __restrict__ b, int nb) {
  int t = threadIdx.x;
  if (t < na) a[t] = 0;
  if (t < nb) b[t] = 0;
}

// ---------------------------------------------------------------------------
// CSR build, stage 1: coarse-bucket histogram, both graphs in one dispatch.
// blocks [0,512) -> inter; [512,768) -> soc.
// ---------------------------------------------------------------------------
__global__ __launch_bounds__(256) void bucket_hist_dual(
    const int* __restrict__ rowsI, int* __restrict__ bCntI,
    const int* __restrict__ rowsS, int* __restrict__ bCntS) {
  __shared__ int h[NB_MAX];
  const int* rows;
  int* bCnt;
  int nE, nB, b0, nBlk;
  if (blockIdx.x < 512) {
    rows = rowsI; bCnt = bCntI; nE = E_INTER; nB = IB_NB; b0 = blockIdx.x;
    nBlk = 512;
  } else {
    rows = rowsS; bCnt = bCntS; nE = E_SOC; nB = SB_NB; b0 = blockIdx.x - 512;
    nBlk = 256;
  }
  for (int i = threadIdx.x; i < nB; i += 256) h[i] = 0;
  __syncthreads();
  int stride = nBlk * 256;
  for (int e = b0 * 256 + threadIdx.x; e < nE; e += stride)
    atomicAdd(&h[rows[e] >> CB_SHIFT], 1);
  __syncthreads();
  for (int i = threadIdx.x; i < nB; i += 256) {
    int v = h[i];
    if (v) atomicAdd(&bCnt[i], v);
  }
}

// 2-block dispatch: exclusive scan over each graph's bucket counts (n<=1024).
__global__ __launch_bounds__(1024) void scan_dual(
    int* __restrict__ cntI, int* __restrict__ bOffI,
    int* __restrict__ cntS, int* __restrict__ bOffS) {
  __shared__ int waveTot[16];
  int* cnt  = blockIdx.x == 0 ? cntI : cntS;
  int* bOff = blockIdx.x == 0 ? bOffI : bOffS;
  int n     = blockIdx.x == 0 ? IB_NB : SB_NB;
  int t = threadIdx.x;
  int lane = t & 63, w = t >> 6;
  int orig = (t < n) ? cnt[t] : 0;
  int v = orig;
  #pragma unroll
  for (int sh = 1; sh < 64; sh <<= 1) {
    int u = __shfl_up(v, sh, 64);
    if (lane >= sh) v += u;
  }
  if (lane == 63) waveTot[w] = v;
  __syncthreads();
  int woff = 0;
  #pragma unroll
  for (int i = 0; i < 16; i++)
    if (i < w) woff += waveTot[i];
  v += woff;
  int excl = v - orig;
  if (t < n) {
    bOff[t] = excl;
    cnt[t] = excl;   // cursor init (cnt aliases bCur)
  }
  if (t == n - 1) bOff[n] = excl + orig;
}

// ---------------------------------------------------------------------------
// stage 2: block-aggregated binning, both graphs in one dispatch.
// pack: [63:32]=valbits  [31:9]=col (23 bits)  [8:0]=row&511
// ---------------------------------------------------------------------------
__global__ __launch_bounds__(256) void bin_dual(
    const int* __restrict__ rowsI, const int* __restrict__ colsI,
    const float* __restrict__ valsI, int* __restrict__ gCurI,
    unsigned long long* __restrict__ tmpI,
    const int* __restrict__ rowsS, const int* __restrict__ colsS,
    const float* __restrict__ valsS, int* __restrict__ gCurS,
    unsigned long long* __restrict__ tmpS) {
  __shared__ int cnt[NB_MAX];
  __shared__ int cur[NB_MAX];
  const int *rows, *cols;
  const float* vals;
  int* gCur;
  unsigned long long* tmp;
  int nE, nB, b0;
  if (blockIdx.x < NBI_CHUNKS) {
    rows = rowsI; cols = colsI; vals = valsI; gCur = gCurI; tmp = tmpI;
    nE = E_INTER; nB = IB_NB; b0 = blockIdx.x;
  } else {
    rows = rowsS; cols = colsS; vals = valsS; gCur = gCurS; tmp = tmpS;
    nE = E_SOC; nB = SB_NB; b0 = blockIdx.x - NBI_CHUNKS;
  }
  int t = threadIdx.x;
  int base = b0 * BIN_CHUNK;
  for (int i = t; i < nB; i += 256) cnt[i] = 0;
  __syncthreads();
  #pragma unroll 4
  for (int i = 0; i < BIN_PER_T; i++) {
    int e = base + t + i * 256;
    if (e < nE) atomicAdd(&cnt[rows[e] >> CB_SHIFT], 1);
  }
  __syncthreads();
  for (int i = t; i < nB; i += 256) {
    int c = cnt[i];
    cur[i] = c ? atomicAdd(&gCur[i], c) : 0;
  }
  __syncthreads();
  #pragma unroll 4
  for (int i = 0; i < BIN_PER_T; i++) {
    int e = base + t + i * 256;
    if (e < nE) {
      int r = rows[e];
      int p = atomicAdd(&cur[r >> CB_SHIFT], 1);
      tmp[p] = ((unsigned long long)__float_as_uint(vals[e]) << 32) |
               ((unsigned long long)(unsigned int)cols[e] << CB_SHIFT) |
               (unsigned long long)(r & (CB_ROWS - 1));
    }
  }
}

// ---------------------------------------------------------------------------
// stage 3: one workgroup per bucket (512 rows); both graphs in one dispatch.
// LDS-hist + LDS scan -> rowPtr, then exact CSR placement.
// ---------------------------------------------------------------------------
__global__ __launch_bounds__(256) void finalize_dual(
    const unsigned long long* __restrict__ tmpI,
    const int* __restrict__ bOffI, int* __restrict__ rowPtrI,
    unsigned long long* __restrict__ pairsI,
    const unsigned long long* __restrict__ tmpS,
    const int* __restrict__ bOffS, int* __restrict__ rowPtrS,
    unsigned long long* __restrict__ pairsS) {
  __shared__ int cur[CB_ROWS];   // 2 KB
  __shared__ int waveTot[4];
  const unsigned long long* tmp;
  const int* bOff;
  int* rowPtr;
  unsigned long long* pairs;
  int nRows, nB, b;
  if (blockIdx.x < IB_NB) {
    tmp = tmpI; bOff = bOffI; rowPtr = rowPtrI; pairs = pairsI;
    nRows = N_NODE; nB = IB_NB; b = blockIdx.x;
  } else {
    tmp = tmpS; bOff = bOffS; rowPtr = rowPtrS; pairs = pairsS;
    nRows = N_USER; nB = SB_NB; b = blockIdx.x - IB_NB;
  }
  int t = threadIdx.x;
  int start = bOff[b];
  int end = bOff[b + 1];
  for (int i = t; i < CB_ROWS; i += 256) cur[i] = 0;
  __syncthreads();
  for (int e = start + t; e < end; e += 256)
    atomicAdd(&cur[(int)(tmp[e] & (unsigned long long)(CB_ROWS - 1))], 1);
  __syncthreads();
  int sbase = t * 2;
  int loc1 = cur[sbase];
  int run = loc1 + cur[sbase + 1];
  int lane = t & 63, w = t >> 6;
  int v = run;
  #pragma unroll
  for (int sh = 1; sh < 64; sh <<= 1) {
    int u = __shfl_up(v, sh, 64);
    if (lane >= sh) v += u;
  }
  if (lane == 63) waveTot[w] = v;
  __syncthreads();
  int woff = 0;
  #pragma unroll
  for (int i = 0; i < 4; i++)
    if (i < w) woff += waveTot[i];
  int toff = (v - run) + woff;
  __syncthreads();
  int rowBase = b << CB_SHIFT;
  {
    cur[sbase] = toff;
    cur[sbase + 1] = toff + loc1;
    int r0 = rowBase + sbase;
    if (r0 < nRows) rowPtr[r0] = start + toff;
    if (r0 + 1 < nRows) rowPtr[r0 + 1] = start + toff + loc1;
  }
  if (b == 0 && t == 0) rowPtr[nRows] = bOff[nB];
  __syncthreads();
  for (int e = start + t; e < end; e += 256) {
    unsigned long long pk = tmp[e];
    int rl = (int)(pk & (unsigned long long)(CB_ROWS - 1));
    int p = start + atomicAdd(&cur[rl], 1);
    pairs[p] = (pk & 0xffffffff00000000ull) |
               ((pk >> CB_SHIFT) & 0x7fffffull);
  }
}

// ---------------------------------------------------------------------------
// init: fused[0] = bf16(ini) (gate at k=0 is identity since z==h and the
// 2-way softmax weights sum to 1), soc[0] = bf16(uE). No f32 scratch.
// ---------------------------------------------------------------------------
__global__ __launch_bounds__(256) void init_convert(
    const float* __restrict__ uE, const float* __restrict__ iE,
    __hip_bfloat16* __restrict__ soc, __hip_bfloat16* __restrict__ fused0) {
  int idx = blockIdx.x * blockDim.x + threadIdx.x;
  if (idx >= NODE_ELEMS) return;
  if (idx < USER_ELEMS) {
    float v = uE[idx];
    soc[idx] = __float2bfloat16(v);
    fused0[idx] = __float2bfloat16(v);
  } else {
    fused0[idx] = __float2bfloat16(iE[idx - USER_ELEMS]);
  }
}

// ---------------------------------------------------------------------------
// pull-SpMM row accumulator: 8-wide main loop, scalarized col/val
// (readfirstlane -> SALU address math, SGPR fma multiplier), epilogue =
// fixed 4-block (rem&4) + small clamped 4-block (rem&3).
// ---------------------------------------------------------------------------
__device__ __forceinline__ float row_accum(
    const int* __restrict__ rowPtr,
    const unsigned long long* __restrict__ pairs,
    const __hip_bfloat16* __restrict__ x, int row, int lane) {
  int start = rowPtr[row];
  int end = rowPtr[row + 1];
  float a0 = 0.f, a1 = 0.f, a2 = 0.f, a3 = 0.f;
  int e = start;
  for (; e + 8 <= end; e += 8) {
    unsigned long long pk[8];
    #pragma unroll
    for (int i = 0; i < 8; i++) pk[i] = pairs[e + i];
    float xv[8], vv[8];
    #pragma unroll
    for (int i = 0; i < 8; i++) {
      int c = __builtin_amdgcn_readfirstlane((int)(unsigned int)pk[i]);
      vv[i] = __uint_as_float(
          __builtin_amdgcn_readfirstlane((unsigned int)(pk[i] >> 32)));
      xv[i] = __bfloat162float(x[c * LATDIM + lane]);
    }
    a0 += vv[0] * xv[0];
    a1 += vv[1] * xv[1];
    a2 += vv[2] * xv[2];
    a3 += vv[3] * xv[3];
    a0 += vv[4] * xv[4];
    a1 += vv[5] * xv[5];
    a2 += vv[6] * xv[6];
    a3 += vv[7] * xv[7];
  }
  int rem = end - e;
  if (rem & 4) {
    unsigned long long pk[4];
    #pragma unroll
    for (int i = 0; i < 4; i++) pk[i] = pairs[e + i];
    float xv[4], vv[4];
    #pragma unroll
    for (int i = 0; i < 4; i++) {
      int c = __builtin_amdgcn_readfirstlane((int)(unsigned int)pk[i]);
      vv[i] = __uint_as_float(
          __builtin_amdgcn_readfirstlane((unsigned int)(pk[i] >> 32)));
      xv[i] = __bfloat162float(x[c * LATDIM + lane]);
    }
    a0 += vv[0] * xv[0];
    a1 += vv[1] * xv[1];
    a2 += vv[2] * xv[2];
    a3 += vv[3] * xv[3];
    e += 4;
  }
  if (e < end) {                      // 1..3 remain
    int last = end - 1;
    unsigned long long pk[4];
    unsigned int vb[4];
    #pragma unroll
    for (int i = 0; i < 4; i++) {
      int ei = e + i;
      int ec = ei < last ? ei : last;          // wave-uniform select
      pk[i] = pairs[ec];
      vb[i] = (ei < end) ? (unsigned int)(pk[i] >> 32) : 0u;
    }
    float xv[4], vv[4];
    #pragma unroll
    for (int i = 0; i < 4; i++) {
      int c = __builtin_amdgcn_readfirstlane((int)(unsigned int)pk[i]);
      vv[i] = __uint_as_float(__builtin_amdgcn_readfirstlane(vb[i]));
      xv[i] = __bfloat162float(x[c * LATDIM + lane]);
    }
    a0 += vv[0] * xv[0];
    a1 += vv[1] * xv[1];
    a2 += vv[2] * xv[2];
    a3 += vv[3] * xv[3];
  }
  return (a0 + a1) + (a2 + a3);
}

// ---------------------------------------------------------------------------
// fused SpMM + gate: one wave per node row (grid = N_NODE waves).
//   user rows: hi = inter-SpMM(fused[k]); z = soc-SpMM(soc[k]);
//              soc[k+1] = bf16(z); gate(z,hi,W_gate[k+1]) -> fused[k+1].
//   item rows: fused[k+1] = bf16(inter-SpMM(fused[k])).
// The gate consumes z,hi in registers: no f32 scratch, no separate fuse pass.
// ---------------------------------------------------------------------------
__global__ __launch_bounds__(256) void spmm_fuse(
    const int* __restrict__ iRowPtr,
    const unsigned long long* __restrict__ iPairs,
    const __hip_bfloat16* __restrict__ xI,
    __hip_bfloat16* __restrict__ fusedNext,
    const int* __restrict__ sRowPtr,
    const unsigned long long* __restrict__ sPairs,
    const __hip_bfloat16* __restrict__ socCur,
    __hip_bfloat16* __restrict__ socNxt,
    const float* __restrict__ W_gate,   // (5,2,128)
    const float* __restrict__ b_gate,   // (5,2)
    int kNext) {
  int g = blockIdx.x * 256 + threadIdx.x;
  int row = __builtin_amdgcn_readfirstlane(g >> 6);
  int lane = g & 63;
  if (row >= N_NODE) return;
  float hi = row_accum(iRowPtr, iPairs, xI, row, lane);
  int off = row * LATDIM + lane;
  if (row < N_USER) {
    float z = row_accum(sRowPtr, sPairs, socCur, row, lane);
    socNxt[off] = __float2bfloat16(z);
    const float* wg = W_gate + kNext * 256;
    float p0 = z * wg[lane] + hi * wg[64 + lane];
    float p1 = z * wg[128 + lane] + hi * wg[192 + lane];
    #pragma unroll
    for (int s = 32; s > 0; s >>= 1) {
      p0 += __shfl_xor(p0, s, 64);
      p1 += __shfl_xor(p1, s, 64);
    }
    p0 += b_gate[kNext * 2 + 0];
    p1 += b_gate[kNext * 2 + 1];
    p0 = p0 >= 0.f ? p0 : 0.01f * p0;   // leaky_relu(0.01)
    p1 = p1 >= 0.f ? p1 : 0.01f * p1;
    float mx = fmaxf(p0, p1);
    float e0 = __expf(p0 - mx);
    float e1 = __expf(p1 - mx);
    float inv = 1.f / (e0 + e1);
    fusedNext[off] = __float2bfloat16(z * (e0 * inv) + hi * (e1 * inv));
  } else {
    fusedNext[off] = __float2bfloat16(hi);
  }
}

// ---------------------------------------------------------------------------
// final: per-row 5-way attention over the 5 fused layers (unchanged)
// ---------------------------------------------------------------------------
__global__ __launch_bounds__(256) void final_kernel(
    const __hip_bfloat16* __restrict__ fused,
    const float* __restrict__ WL1,     // (5,320)
    const float* __restrict__ bL1,     // (5,)
    const float* __restrict__ WL2,
    const float* __restrict__ bL2,
    float* __restrict__ out) {
  int g = blockIdx.x * blockDim.x + threadIdx.x;
  int row = g >> 6;
  int lane = g & 63;
  if (row >= N_NODE) return;

  float f[5];
  #pragma unroll
  for (int k = 0; k < 5; k++)
    f[k] = __bfloat162float(fused[(size_t)k * NODE_ELEMS + row * LATDIM + lane]);

  const float* WL = (row < N_USER) ? WL1 : WL2;
  const float* bL = (row < N_USER) ? bL1 : bL2;

  float p[5];
  #pragma unroll
  for (int j = 0; j < 5; j++) {
    float s = 0.f;
    #pragma unroll
    for (int k = 0; k < 5; k++)
      s += f[k] * WL[j * 320 + k * 64 + lane];
    p[j] = s;
  }
  #pragma unroll
  for (int s = 32; s > 0; s >>= 1) {
    #pragma unroll
    for (int j = 0; j < 5; j++) p[j] += __shfl_xor(p[j], s, 64);
  }
  float mx = -1e30f;
  #pragma unroll
  for (int j = 0; j < 5; j++) {
    p[j] += bL[j];
    p[j] = p[j] >= 0.f ? p[j] : 0.01f * p[j];
    mx = fmaxf(mx, p[j]);
  }
  float sum = 0.f;
  #pragma unroll
  for (int j = 0; j < 5; j++) {
    p[j] = __expf(p[j] - mx);
    sum += p[j];
  }
  float inv = 1.f / sum;
  float o = 0.f;
  #pragma unroll
  for (int j = 0; j < 5; j++) o += (p[j] * inv) * f[j];
  out[row * LATDIM + lane] = o;
}

// ---------------------------------------------------------------------------
extern "C" void kernel_launch(void* const* d_in, const int* in_sizes, int n_in,
                              void* d_out, int out_size, void* d_ws,
                              size_t ws_size, hipStream_t stream) {
  const float* uE     = (const float*)d_in[0];
  const float* iE     = (const float*)d_in[1];
  const float* W_gate = (const float*)d_in[2];
  const float* b_gate = (const float*)d_in[3];
  const float* WL1    = (const float*)d_in[4];
  const float* bL1    = (const float*)d_in[5];
  const float* WL2    = (const float*)d_in[6];
  const float* bL2    = (const float*)d_in[7];
  const int* inter_rows = (const int*)d_in[8];
  const int* inter_cols = (const int*)d_in[9];
  const float* inter_vals = (const float*)d_in[10];
  const int* soc_rows   = (const int*)d_in[11];
  const int* soc_cols   = (const int*)d_in[12];
  const float* soc_vals = (const float*)d_in[13];
  float* out = (float*)d_out;

  if (ws_size < WS_REQUIRED) {
    float v = (float)(ws_size / (1024ull * 1024ull));
    fill_diag<<<(out_size + 255) / 256, 256, 0, stream>>>(out, out_size, v);
    return;
  }

  char* ws = (char*)d_ws;
  __hip_bfloat16* socBuf[2] = {(__hip_bfloat16*)ws,
                               (__hip_bfloat16*)(ws + SOC_BYTES)};
  __hip_bfloat16* fused = (__hip_bfloat16*)(ws + FUSED_OFF);
  unsigned long long* tmpI = (unsigned long long*)(ws + FUSED_OFF);
  unsigned long long* tmpS = (unsigned long long*)(ws + FUSED_OFF + 32000000);
  unsigned long long* iPairs = (unsigned long long*)(ws + IPAIR_OFF);
  unsigned long long* sPairs = (unsigned long long*)(ws + SPAIR_OFF);
  int* iRowPtr = (int*)(ws + IRP_OFF);
  int* iBOff   = (int*)(ws + IBOFF_OFF);
  int* iBCur   = (int*)(ws + IBCUR_OFF);
  int* sRowPtr = (int*)(ws + SRP_OFF);
  int* sBOff   = (int*)(ws + SBOFF_OFF);
  int* sBCur   = (int*)(ws + SBCUR_OFF);

  // ---- CSR build: both graphs, dual-dispatch radix ----
  zero_dual<<<1, 1024, 0, stream>>>(iBCur, IB_NB, sBCur, SB_NB);
  bucket_hist_dual<<<768, 256, 0, stream>>>(inter_rows, iBCur, soc_rows, sBCur);
  scan_dual<<<2, 1024, 0, stream>>>(iBCur, iBOff, sBCur, sBOff);
  bin_dual<<<NBI_CHUNKS + NBS_CHUNKS, 256, 0, stream>>>(
      inter_rows, inter_cols, inter_vals, iBCur, tmpI,
      soc_rows, soc_cols, soc_vals, sBCur, tmpS);
  finalize_dual<<<IB_NB + SB_NB, 256, 0, stream>>>(
      tmpI, iBOff, iRowPtr, iPairs, tmpS, sBOff, sRowPtr, sPairs);

  // ---- main pipeline ----
  init_convert<<<NODE_ELEMS / 256, 256, 0, stream>>>(uE, iE, socBuf[0], fused);

  for (int k = 0; k < 4; k++) {
    __hip_bfloat16* fk = fused + (size_t)k * NODE_ELEMS;
    spmm_fuse<<<NODE_ELEMS / 256, 256, 0, stream>>>(
        iRowPtr, iPairs, fk, fk + NODE_ELEMS,
        sRowPtr, sPairs, socBuf[k & 1], socBuf[(k + 1) & 1],
        W_gate, b_gate, k + 1);
  }

  final_kernel<<<NODE_ELEMS / 256, 256, 0, stream>>>(fused, WL1, bL1, WL2, bL2,
                                                     out);
}

// Round 8
// 1030.954 us; speedup vs baseline: 1.9834x; 1.0279x over previous
//
#include <hip/hip_runtime.h>
#include <hip/hip_bf16.h>

#define N_USER 100000
#define N_ITEM 200000
#define N_NODE 300000
#define LATDIM 64
#define E_INTER 4000000
#define E_SOC  2000000

#define NODE_ELEMS (N_NODE * LATDIM)   // 19,200,000
#define USER_ELEMS (N_USER * LATDIM)   // 6,400,000

// CSR-build radix: inter buckets = 512 rows (shift 9), soc = 256 rows
// (shift 8) so a bucket's edges (~6.8K / ~5.1K avg) fit the 8192-edge LDS
// stage in finalize. Fallback path handles overflow.
#define ISHIFT 9
#define SSHIFT 8
#define IB_NB ((N_NODE + 511) >> ISHIFT)   // 586
#define SB_NB ((N_USER + 255) >> SSHIFT)   // 391
#define NB_MAX 640

#define BIN_PER_T 32
#define BIN_CHUNK (256 * BIN_PER_T)    // 8192 edges per block
#define NBI_CHUNKS ((E_INTER + BIN_CHUNK - 1) / BIN_CHUNK)   // 489
#define NBS_CHUNKS ((E_SOC + BIN_CHUNK - 1) / BIN_CHUNK)     // 245
#define FCAP 8192                      // LDS edge capacity (64 KB)

typedef unsigned long long u64;

// ---------------------------------------------------------------------------
// workspace layout (bytes) -- within the verified 268,802,304 budget:
//   socA     bf16[USER_ELEMS]        @ 0            12,800,000
//   socB     bf16[USER_ELEMS]        @ 12,800,000   12,800,000
//   fused    bf16[5*NODE_ELEMS]      @ 25,600,000  192,000,000
//     (CSR-build phase aliases tmpI/tmpS onto fused while it is dead)
//   iPairs   u64 [E_INTER]           @ 217,600,000  32,000,000
//   sPairs   u64 [E_SOC]             @ 249,600,000  16,000,000
//   iRowPtr  i32 [N_NODE+1]          @ 265,600,000
//   iBOff    i32 [<=640+1]           @ 266,800,128
//   iBCur    i32 [<=640]             @ 266,802,688
//   sRowPtr  i32 [N_USER+1]          @ 268,000,128
//   sBOff    i32 [<=640+1]           @ 268,400,256
//   sBCur    i32 [<=640]             @ 268,402,816
#define SOC_BYTES 12800000
#define FUSED_OFF 25600000
#define IPAIR_OFF 217600000
#define SPAIR_OFF 249600000
#define IRP_OFF   265600000
#define IBOFF_OFF 266800128
#define IBCUR_OFF 266802688
#define SRP_OFF   268000128
#define SBOFF_OFF 268400256
#define SBCUR_OFF 268402816
#define WS_REQUIRED 268802304ull

// ---------------------------------------------------------------------------
__global__ __launch_bounds__(256) void fill_diag(float* __restrict__ o, int n,
                                                 float v) {
  int i = blockIdx.x * blockDim.x + threadIdx.x;
  if (i < n) o[i] = v;
}

__global__ __launch_bounds__(1024) void zero_dual(int* __restrict__ a, int na,
                                                  int* __restrict__ b, int nb) {
  int t = threadIdx.x;
  if (t < na) a[t] = 0;
  if (t < nb) b[t] = 0;
}

// ---------------------------------------------------------------------------
// stage 1: coarse-bucket histogram, both graphs, int4-vectorized row reads.
// blocks [0,512) -> inter; [512,768) -> soc. (nE % 4 == 0 for both.)
// ---------------------------------------------------------------------------
__global__ __launch_bounds__(256) void bucket_hist_dual(
    const int* __restrict__ rowsI, int* __restrict__ bCntI,
    const int* __restrict__ rowsS, int* __restrict__ bCntS) {
  __shared__ int h[NB_MAX];
  const int4* rows4;
  int* bCnt;
  int nQ, nB, b0, nBlk, shift;
  if (blockIdx.x < 512) {
    rows4 = (const int4*)rowsI; bCnt = bCntI; nQ = E_INTER / 4; nB = IB_NB;
    b0 = blockIdx.x; nBlk = 512; shift = ISHIFT;
  } else {
    rows4 = (const int4*)rowsS; bCnt = bCntS; nQ = E_SOC / 4; nB = SB_NB;
    b0 = blockIdx.x - 512; nBlk = 256; shift = SSHIFT;
  }
  for (int i = threadIdx.x; i < nB; i += 256) h[i] = 0;
  __syncthreads();
  int stride = nBlk * 256;
  for (int q = b0 * 256 + threadIdx.x; q < nQ; q += stride) {
    int4 r = rows4[q];
    atomicAdd(&h[r.x >> shift], 1);
    atomicAdd(&h[r.y >> shift], 1);
    atomicAdd(&h[r.z >> shift], 1);
    atomicAdd(&h[r.w >> shift], 1);
  }
  __syncthreads();
  for (int i = threadIdx.x; i < nB; i += 256) {
    int v = h[i];
    if (v) atomicAdd(&bCnt[i], v);
  }
}

// 2-block dispatch: exclusive scan over each graph's bucket counts (n<=1024).
__global__ __launch_bounds__(1024) void scan_dual(
    int* __restrict__ cntI, int* __restrict__ bOffI,
    int* __restrict__ cntS, int* __restrict__ bOffS) {
  __shared__ int waveTot[16];
  int* cnt  = blockIdx.x == 0 ? cntI : cntS;
  int* bOff = blockIdx.x == 0 ? bOffI : bOffS;
  int n     = blockIdx.x == 0 ? IB_NB : SB_NB;
  int t = threadIdx.x;
  int lane = t & 63, w = t >> 6;
  int orig = (t < n) ? cnt[t] : 0;
  int v = orig;
  #pragma unroll
  for (int sh = 1; sh < 64; sh <<= 1) {
    int u = __shfl_up(v, sh, 64);
    if (lane >= sh) v += u;
  }
  if (lane == 63) waveTot[w] = v;
  __syncthreads();
  int woff = 0;
  #pragma unroll
  for (int i = 0; i < 16; i++)
    if (i < w) woff += waveTot[i];
  v += woff;
  int excl = v - orig;
  if (t < n) {
    bOff[t] = excl;
    cnt[t] = excl;   // cursor init (cnt aliases bCur)
  }
  if (t == n - 1) bOff[n] = excl + orig;
}

// ---------------------------------------------------------------------------
// stage 2: LDS-staged binning. Per block: hist its 8192 edges, local scan,
// ONE global atomic per (block,bucket), bucket-sort edges in LDS, then copy
// each bucket run out as a dense wave-burst (sequential stores -> clean
// write-combining; no cross-XCD partial-line scatter).
// pack: [63:32]=valbits  [31:shift]=col  [shift-1:0]=row&(rows-1)
// ---------------------------------------------------------------------------
__global__ __launch_bounds__(256) void bin_dual(
    const int* __restrict__ rowsI, const int* __restrict__ colsI,
    const float* __restrict__ valsI, int* __restrict__ gCurI,
    u64* __restrict__ tmpI,
    const int* __restrict__ rowsS, const int* __restrict__ colsS,
    const float* __restrict__ valsS, int* __restrict__ gCurS,
    u64* __restrict__ tmpS) {
  __shared__ int cnt[NB_MAX];
  __shared__ int cur[NB_MAX];
  __shared__ int gB[NB_MAX];
  __shared__ int waveTot[4];
  extern __shared__ u64 ldsE[];        // FCAP = 8192 edges, 64 KB
  const int *rows, *cols;
  const float* vals;
  int* gCur;
  u64* tmp;
  int nE, nB, b0, shift;
  if (blockIdx.x < NBI_CHUNKS) {
    rows = rowsI; cols = colsI; vals = valsI; gCur = gCurI; tmp = tmpI;
    nE = E_INTER; nB = IB_NB; b0 = blockIdx.x; shift = ISHIFT;
  } else {
    rows = rowsS; cols = colsS; vals = valsS; gCur = gCurS; tmp = tmpS;
    nE = E_SOC; nB = SB_NB; b0 = blockIdx.x - NBI_CHUNKS; shift = SSHIFT;
  }
  int t = threadIdx.x;
  int base = b0 * BIN_CHUNK;
  int rmask = (1 << shift) - 1;
  for (int i = t; i < nB; i += 256) cnt[i] = 0;
  __syncthreads();
  // pass 1: histogram (rows only)
  #pragma unroll 4
  for (int i = 0; i < BIN_PER_T; i++) {
    int e = base + t + i * 256;
    if (e < nE) atomicAdd(&cnt[rows[e] >> shift], 1);
  }
  __syncthreads();
  // pass 2: local exclusive scan (3 entries/thread) -> cur
  {
    int i0 = t * 3;
    int c0 = (i0 < nB) ? cnt[i0] : 0;
    int c1 = (i0 + 1 < nB) ? cnt[i0 + 1] : 0;
    int c2 = (i0 + 2 < nB) ? cnt[i0 + 2] : 0;
    int tsum = c0 + c1 + c2;
    int lane = t & 63, w = t >> 6;
    int v = tsum;
    #pragma unroll
    for (int sh = 1; sh < 64; sh <<= 1) {
      int u = __shfl_up(v, sh, 64);
      if (lane >= sh) v += u;
    }
    if (lane == 63) waveTot[w] = v;
    __syncthreads();
    int woff = 0;
    #pragma unroll
    for (int i = 0; i < 4; i++)
      if (i < w) woff += waveTot[i];
    int toff = (v - tsum) + woff;
    if (i0 < nB) cur[i0] = toff;
    if (i0 + 1 < nB) cur[i0 + 1] = toff + c0;
    if (i0 + 2 < nB) cur[i0 + 2] = toff + c0 + c1;
  }
  __syncthreads();
  // global reservation: one atomic per (block,bucket)
  for (int i = t; i < nB; i += 256) {
    int c = cnt[i];
    gB[i] = c ? atomicAdd(&gCur[i], c) : 0;
  }
  __syncthreads();
  // pass 3: scatter edges into LDS bucket-major
  #pragma unroll 4
  for (int i = 0; i < BIN_PER_T; i++) {
    int e = base + t + i * 256;
    if (e < nE) {
      int r = rows[e];
      int p = atomicAdd(&cur[r >> shift], 1);
      ldsE[p] = ((u64)__float_as_uint(vals[e]) << 32) |
                ((u64)(unsigned int)cols[e] << shift) |
                (u64)(r & rmask);
    }
  }
  __syncthreads();
  // pass 4: copy runs out; one wave per bucket, round-robin
  int w = t >> 6, lane = t & 63;
  for (int i = w; i < nB; i += 4) {
    int c = cnt[i];
    if (!c) continue;
    int src = cur[i] - c;   // cur[i] == loff_i + cnt_i now
    int dst = gB[i];
    for (int j = lane; j < c; j += 64) tmp[dst + j] = ldsE[src + j];
  }
}

// ---------------------------------------------------------------------------
// stage 3: one 512-thread block per bucket. Edges kept in LDS from pass 1
// (global fallback if bucket > FCAP). LDS hist + scan -> rowPtr, then exact
// CSR placement within the bucket's window.
// ---------------------------------------------------------------------------
__global__ __launch_bounds__(512) void finalize_dual(
    const u64* __restrict__ tmpI, const int* __restrict__ bOffI,
    int* __restrict__ rowPtrI, u64* __restrict__ pairsI,
    const u64* __restrict__ tmpS, const int* __restrict__ bOffS,
    int* __restrict__ rowPtrS, u64* __restrict__ pairsS) {
  __shared__ int cur[512];
  __shared__ int waveTot[8];
  extern __shared__ u64 ldsE[];        // FCAP edges
  const u64* tmp;
  const int* bOff;
  int* rowPtr;
  u64* pairs;
  int nRows, nB, b, shift;
  if (blockIdx.x < IB_NB) {
    tmp = tmpI; bOff = bOffI; rowPtr = rowPtrI; pairs = pairsI;
    nRows = N_NODE; nB = IB_NB; b = blockIdx.x; shift = ISHIFT;
  } else {
    tmp = tmpS; bOff = bOffS; rowPtr = rowPtrS; pairs = pairsS;
    nRows = N_USER; nB = SB_NB; b = blockIdx.x - IB_NB; shift = SSHIFT;
  }
  int t = threadIdx.x;
  int rmask = (1 << shift) - 1;
  int start = bOff[b];
  int end = bOff[b + 1];
  int n = end - start;
  bool fits = (n <= FCAP);
  cur[t] = 0;
  __syncthreads();
  if (fits) {
    for (int j = t; j < n; j += 512) {
      u64 pk = tmp[start + j];
      ldsE[j] = pk;
      atomicAdd(&cur[(int)(pk & (u64)rmask)], 1);
    }
  } else {
    for (int j = t; j < n; j += 512)
      atomicAdd(&cur[(int)(tmp[start + j] & (u64)rmask)], 1);
  }
  __syncthreads();
  // exclusive scan over cur[0..512): one entry/thread
  int orig = cur[t];
  int lane = t & 63, w = t >> 6;
  int v = orig;
  #pragma unroll
  for (int sh = 1; sh < 64; sh <<= 1) {
    int u = __shfl_up(v, sh, 64);
    if (lane >= sh) v += u;
  }
  if (lane == 63) waveTot[w] = v;
  __syncthreads();
  int woff = 0;
  #pragma unroll
  for (int i = 0; i < 8; i++)
    if (i < w) woff += waveTot[i];
  int excl = (v - orig) + woff;
  cur[t] = excl;
  int rowsLoc = 1 << shift;
  int row = (b << shift) + t;
  if (t < rowsLoc && row < nRows) rowPtr[row] = start + excl;
  if (b == 0 && t == 0) rowPtr[nRows] = bOff[nB];
  __syncthreads();
  if (fits) {
    for (int j = t; j < n; j += 512) {
      u64 pk = ldsE[j];
      unsigned int lo = (unsigned int)pk;
      int p = start + atomicAdd(&cur[(int)(lo & (unsigned)rmask)], 1);
      pairs[p] = (pk & 0xffffffff00000000ull) | (lo >> shift);
    }
  } else {
    for (int j = t; j < n; j += 512) {
      u64 pk = tmp[start + j];
      unsigned int lo = (unsigned int)pk;
      int p = start + atomicAdd(&cur[(int)(lo & (unsigned)rmask)], 1);
      pairs[p] = (pk & 0xffffffff00000000ull) | (lo >> shift);
    }
  }
}

// ---------------------------------------------------------------------------
// init: fused[0] = bf16(ini), soc[0] = bf16(uE). float4 loads, packed stores.
// ---------------------------------------------------------------------------
__device__ __forceinline__ unsigned int pack2bf(float a, float b) {
  __hip_bfloat16 ba = __float2bfloat16(a);
  __hip_bfloat16 bb = __float2bfloat16(b);
  unsigned short ua = *(unsigned short*)&ba;
  unsigned short ub = *(unsigned short*)&bb;
  return (unsigned int)ua | ((unsigned int)ub << 16);
}

__global__ __launch_bounds__(256) void init_convert(
    const float* __restrict__ uE, const float* __restrict__ iE,
    __hip_bfloat16* __restrict__ soc, __hip_bfloat16* __restrict__ fused0) {
  int q = blockIdx.x * blockDim.x + threadIdx.x;   // quad index
  if (q >= NODE_ELEMS / 4) return;
  uint2* f4 = (uint2*)fused0;
  if (q < USER_ELEMS / 4) {
    float4 v = ((const float4*)uE)[q];
    uint2 p;
    p.x = pack2bf(v.x, v.y);
    p.y = pack2bf(v.z, v.w);
    ((uint2*)soc)[q] = p;
    f4[q] = p;
  } else {
    float4 v = ((const float4*)iE)[q - USER_ELEMS / 4];
    uint2 p;
    p.x = pack2bf(v.x, v.y);
    p.y = pack2bf(v.z, v.w);
    f4[q] = p;
  }
}

// ---------------------------------------------------------------------------
// pull-SpMM accum helpers: 8-wide batch (scalarized col/val) + tail.
// ---------------------------------------------------------------------------
__device__ __forceinline__ void accum8(
    const u64* __restrict__ pairs, int e, const __hip_bfloat16* __restrict__ x,
    int lane, float& a0, float& a1, float& a2, float& a3) {
  u64 pk[8];
  #pragma unroll
  for (int i = 0; i < 8; i++) pk[i] = pairs[e + i];
  float xv[8], vv[8];
  #pragma unroll
  for (int i = 0; i < 8; i++) {
    int c = __builtin_amdgcn_readfirstlane((int)(unsigned int)pk[i]);
    vv[i] = __uint_as_float(
        __builtin_amdgcn_readfirstlane((unsigned int)(pk[i] >> 32)));
    xv[i] = __bfloat162float(x[c * LATDIM + lane]);
  }
  a0 += vv[0] * xv[0];
  a1 += vv[1] * xv[1];
  a2 += vv[2] * xv[2];
  a3 += vv[3] * xv[3];
  a0 += vv[4] * xv[4];
  a1 += vv[5] * xv[5];
  a2 += vv[6] * xv[6];
  a3 += vv[7] * xv[7];
}

__device__ __forceinline__ void accum_tail(
    const u64* __restrict__ pairs, int e, int end,
    const __hip_bfloat16* __restrict__ x, int lane,
    float& a0, float& a1, float& a2, float& a3) {
  int rem = end - e;
  if (rem & 4) {
    u64 pk[4];
    #pragma unroll
    for (int i = 0; i < 4; i++) pk[i] = pairs[e + i];
    float xv[4], vv[4];
    #pragma unroll
    for (int i = 0; i < 4; i++) {
      int c = __builtin_amdgcn_readfirstlane((int)(unsigned int)pk[i]);
      vv[i] = __uint_as_float(
          __builtin_amdgcn_readfirstlane((unsigned int)(pk[i] >> 32)));
      xv[i] = __bfloat162float(x[c * LATDIM + lane]);
    }
    a0 += vv[0] * xv[0];
    a1 += vv[1] * xv[1];
    a2 += vv[2] * xv[2];
    a3 += vv[3] * xv[3];
    e += 4;
  }
  if (e < end) {                      // 1..3 remain
    int last = end - 1;
    u64 pk[4];
    unsigned int vb[4];
    #pragma unroll
    for (int i = 0; i < 4; i++) {
      int ei = e + i;
      int ec = ei < last ? ei : last;          // wave-uniform select
      pk[i] = pairs[ec];
      vb[i] = (ei < end) ? (unsigned int)(pk[i] >> 32) : 0u;
    }
    float xv[4], vv[4];
    #pragma unroll
    for (int i = 0; i < 4; i++) {
      int c = __builtin_amdgcn_readfirstlane((int)(unsigned int)pk[i]);
      vv[i] = __uint_as_float(__builtin_amdgcn_readfirstlane(vb[i]));
      xv[i] = __bfloat162float(x[c * LATDIM + lane]);
    }
    a0 += vv[0] * xv[0];
    a1 += vv[1] * xv[1];
    a2 += vv[2] * xv[2];
    a3 += vv[3] * xv[3];
  }
}

// ---------------------------------------------------------------------------
// fused SpMM + gate. User rows interleave the two independent gather streams
// (inter + soc) 8+8-wide -> 16 loads in flight per wave; item rows: inter
// only. Per-chain summation order identical to round 7 (absmax-stable).
// ---------------------------------------------------------------------------
__global__ __launch_bounds__(256) void spmm_fuse(
    const int* __restrict__ iRowPtr, const u64* __restrict__ iPairs,
    const __hip_bfloat16* __restrict__ xI,
    __hip_bfloat16* __restrict__ fusedNext,
    const int* __restrict__ sRowPtr, const u64* __restrict__ sPairs,
    const __hip_bfloat16* __restrict__ socCur,
    __hip_bfloat16* __restrict__ socNxt,
    const float* __restrict__ W_gate,   // (5,2,128)
    const float* __restrict__ b_gate,   // (5,2)
    int kNext) {
  int g = blockIdx.x * 256 + threadIdx.x;
  int row = __builtin_amdgcn_readfirstlane(g >> 6);
  int lane = g & 63;
  if (row >= N_NODE) return;
  int off = row * LATDIM + lane;
  int iS = iRowPtr[row], iE = iRowPtr[row + 1];
  float a0 = 0.f, a1 = 0.f, a2 = 0.f, a3 = 0.f;
  if (row < N_USER) {
    int sS = sRowPtr[row], sE = sRowPtr[row + 1];
    float b0 = 0.f, b1 = 0.f, b2 = 0.f, b3 = 0.f;
    while (iS + 8 <= iE && sS + 8 <= sE) {
      accum8(iPairs, iS, xI, lane, a0, a1, a2, a3);
      accum8(sPairs, sS, socCur, lane, b0, b1, b2, b3);
      iS += 8;
      sS += 8;
    }
    for (; iS + 8 <= iE; iS += 8) accum8(iPairs, iS, xI, lane, a0, a1, a2, a3);
    accum_tail(iPairs, iS, iE, xI, lane, a0, a1, a2, a3);
    for (; sS + 8 <= sE; sS += 8)
      accum8(sPairs, sS, socCur, lane, b0, b1, b2, b3);
    accum_tail(sPairs, sS, sE, socCur, lane, b0, b1, b2, b3);
    float hi = (a0 + a1) + (a2 + a3);
    float z = (b0 + b1) + (b2 + b3);
    socNxt[off] = __float2bfloat16(z);
    const float* wg = W_gate + kNext * 256;
    float p0 = z * wg[lane] + hi * wg[64 + lane];
    float p1 = z * wg[128 + lane] + hi * wg[192 + lane];
    #pragma unroll
    for (int s = 32; s > 0; s >>= 1) {
      p0 += __shfl_xor(p0, s, 64);
      p1 += __shfl_xor(p1, s, 64);
    }
    p0 += b_gate[kNext * 2 + 0];
    p1 += b_gate[kNext * 2 + 1];
    p0 = p0 >= 0.f ? p0 : 0.01f * p0;   // leaky_relu(0.01)
    p1 = p1 >= 0.f ? p1 : 0.01f * p1;
    float mx = fmaxf(p0, p1);
    float e0 = __expf(p0 - mx);
    float e1 = __expf(p1 - mx);
    float inv = 1.f / (e0 + e1);
    fusedNext[off] = __float2bfloat16(z * (e0 * inv) + hi * (e1 * inv));
  } else {
    for (; iS + 8 <= iE; iS += 8) accum8(iPairs, iS, xI, lane, a0, a1, a2, a3);
    accum_tail(iPairs, iS, iE, xI, lane, a0, a1, a2, a3);
    fusedNext[off] = __float2bfloat16((a0 + a1) + (a2 + a3));
  }
}

// ---------------------------------------------------------------------------
// final: 5-way attention; 2 rows/wave (half-waves), 2 dims/lane, dword
// fused loads, float2 WL loads and float2 output stores.
// N_USER is even -> a wave's two rows never straddle the user/item boundary.
// ---------------------------------------------------------------------------
__global__ __launch_bounds__(256) void final_kernel(
    const __hip_bfloat16* __restrict__ fused,
    const float* __restrict__ WL1,     // (5,320)
    const float* __restrict__ bL1,     // (5,)
    const float* __restrict__ WL2,
    const float* __restrict__ bL2,
    float* __restrict__ out) {
  int g = blockIdx.x * blockDim.x + threadIdx.x;
  int row = g >> 5;
  int l = g & 31;            // lane-in-half, handles dims 2l, 2l+1
  if (row >= N_NODE) return;

  float f0[5], f1[5];
  #pragma unroll
  for (int k = 0; k < 5; k++) {
    unsigned int u = *(const unsigned int*)(fused + (size_t)k * NODE_ELEMS +
                                            (size_t)row * LATDIM + 2 * l);
    f0[k] = __uint_as_float(u << 16);
    f1[k] = __uint_as_float(u & 0xffff0000u);
  }

  const float* WL = (row < N_USER) ? WL1 : WL2;
  const float* bL = (row < N_USER) ? bL1 : bL2;

  float p[5];
  #pragma unroll
  for (int j = 0; j < 5; j++) {
    float s = 0.f;
    #pragma unroll
    for (int k = 0; k < 5; k++) {
      float2 w = *(const float2*)(WL + j * 320 + k * 64 + 2 * l);
      s += f0[k] * w.x + f1[k] * w.y;
    }
    p[j] = s;
  }
  #pragma unroll
  for (int s = 16; s > 0; s >>= 1) {
    #pragma unroll
    for (int j = 0; j < 5; j++) p[j] += __shfl_xor(p[j], s, 64);
  }
  float mx = -1e30f;
  #pragma unroll
  for (int j = 0; j < 5; j++) {
    p[j] += bL[j];
    p[j] = p[j] >= 0.f ? p[j] : 0.01f * p[j];
    mx = fmaxf(mx, p[j]);
  }
  float sum = 0.f;
  #pragma unroll
  for (int j = 0; j < 5; j++) {
    p[j] = __expf(p[j] - mx);
    sum += p[j];
  }
  float inv = 1.f / sum;
  float o0 = 0.f, o1 = 0.f;
  #pragma unroll
  for (int j = 0; j < 5; j++) {
    float wj = p[j] * inv;
    o0 += wj * f0[j];
    o1 += wj * f1[j];
  }
  float2 o;
  o.x = o0;
  o.y = o1;
  *(float2*)(out + (size_t)row * LATDIM + 2 * l) = o;
}

// ---------------------------------------------------------------------------
extern "C" void kernel_launch(void* const* d_in, const int* in_sizes, int n_in,
                              void* d_out, int out_size, void* d_ws,
                              size_t ws_size, hipStream_t stream) {
  const float* uE     = (const float*)d_in[0];
  const float* iE     = (const float*)d_in[1];
  const float* W_gate = (const float*)d_in[2];
  const float* b_gate = (const float*)d_in[3];
  const float* WL1    = (const float*)d_in[4];
  const float* bL1    = (const float*)d_in[5];
  const float* WL2    = (const float*)d_in[6];
  const float* bL2    = (const float*)d_in[7];
  const int* inter_rows = (const int*)d_in[8];
  const int* inter_cols = (const int*)d_in[9];
  const float* inter_vals = (const float*)d_in[10];
  const int* soc_rows   = (const int*)d_in[11];
  const int* soc_cols   = (const int*)d_in[12];
  const float* soc_vals = (const float*)d_in[13];
  float* out = (float*)d_out;

  if (ws_size < WS_REQUIRED) {
    float v = (float)(ws_size / (1024ull * 1024ull));
    fill_diag<<<(out_size + 255) / 256, 256, 0, stream>>>(out, out_size, v);
    return;
  }

  char* ws = (char*)d_ws;
  __hip_bfloat16* socBuf[2] = {(__hip_bfloat16*)ws,
                               (__hip_bfloat16*)(ws + SOC_BYTES)};
  __hip_bfloat16* fused = (__hip_bfloat16*)(ws + FUSED_OFF);
  u64* tmpI = (u64*)(ws + FUSED_OFF);
  u64* tmpS = (u64*)(ws + FUSED_OFF + 32000000);
  u64* iPairs = (u64*)(ws + IPAIR_OFF);
  u64* sPairs = (u64*)(ws + SPAIR_OFF);
  int* iRowPtr = (int*)(ws + IRP_OFF);
  int* iBOff   = (int*)(ws + IBOFF_OFF);
  int* iBCur   = (int*)(ws + IBCUR_OFF);
  int* sRowPtr = (int*)(ws + SRP_OFF);
  int* sBOff   = (int*)(ws + SBOFF_OFF);
  int* sBCur   = (int*)(ws + SBCUR_OFF);

  // ---- CSR build ----
  zero_dual<<<1, 1024, 0, stream>>>(iBCur, IB_NB, sBCur, SB_NB);
  bucket_hist_dual<<<768, 256, 0, stream>>>(inter_rows, iBCur, soc_rows, sBCur);
  scan_dual<<<2, 1024, 0, stream>>>(iBCur, iBOff, sBCur, sBOff);
  bin_dual<<<NBI_CHUNKS + NBS_CHUNKS, 256, FCAP * 8, stream>>>(
      inter_rows, inter_cols, inter_vals, iBCur, tmpI,
      soc_rows, soc_cols, soc_vals, sBCur, tmpS);
  finalize_dual<<<IB_NB + SB_NB, 512, FCAP * 8, stream>>>(
      tmpI, iBOff, iRowPtr, iPairs, tmpS, sBOff, sRowPtr, sPairs);

  // ---- main pipeline ----
  init_convert<<<NODE_ELEMS / 4 / 256, 256, 0, stream>>>(uE, iE, socBuf[0],
                                                         fused);

  for (int k = 0; k < 4; k++) {
    __hip_bfloat16* fk = fused + (size_t)k * NODE_ELEMS;
    spmm_fuse<<<NODE_ELEMS / 256, 256, 0, stream>>>(
        iRowPtr, iPairs, fk, fk + NODE_ELEMS,
        sRowPtr, sPairs, socBuf[k & 1], socBuf[(k + 1) & 1],
        W_gate, b_gate, k + 1);
  }

  final_kernel<<<(N_NODE * 32) / 256, 256, 0, stream>>>(fused, WL1, bL1, WL2,
                                                        bL2, out);
}

// Round 9
// 948.733 us; speedup vs baseline: 2.1553x; 1.0867x over previous
//
#include <hip/hip_runtime.h>
#include <hip/hip_bf16.h>

#define N_USER 100000
#define N_ITEM 200000
#define N_NODE 300000
#define LATDIM 64
#define E_INTER 4000000
#define E_SOC  2000000

#define NODE_ELEMS (N_NODE * LATDIM)   // 19,200,000
#define USER_ELEMS (N_USER * LATDIM)   // 6,400,000

// CSR-build radix: inter buckets = 512 rows (shift 9), soc = 256 rows
// (shift 8) so a bucket's edges (~6.8K / ~5.1K avg) fit the 8192-edge LDS
// stage in finalize. Fallback path handles overflow.
#define ISHIFT 9
#define SSHIFT 8
#define IB_NB ((N_NODE + 511) >> ISHIFT)   // 586
#define SB_NB ((N_USER + 255) >> SSHIFT)   // 391
#define NB_MAX 640

#define BIN_PER_T 32
#define BIN_CHUNK (256 * BIN_PER_T)    // 8192 edges per block
#define NBI_CHUNKS ((E_INTER + BIN_CHUNK - 1) / BIN_CHUNK)   // 489
#define NBS_CHUNKS ((E_SOC + BIN_CHUNK - 1) / BIN_CHUNK)     // 245
#define FCAP 8192                      // LDS edge capacity (64 KB)

typedef unsigned long long u64;

// ---------------------------------------------------------------------------
// workspace layout (bytes) -- within the verified 268,802,304 budget:
//   socA     bf16[USER_ELEMS]        @ 0            12,800,000
//   socB     bf16[USER_ELEMS]        @ 12,800,000   12,800,000
//   fused    bf16[5*NODE_ELEMS]      @ 25,600,000  192,000,000
//     (only layers 0..3 are materialized now; layer-4 slot is scratch.
//      CSR-build phase aliases tmpI/tmpS onto fused while it is dead)
//   iPairs   u64 [E_INTER]           @ 217,600,000  32,000,000
//   sPairs   u64 [E_SOC]             @ 249,600,000  16,000,000
//   iRowPtr  i32 [N_NODE+1]          @ 265,600,000
//   iBOff    i32 [<=640+1]           @ 266,800,128
//   iBCur    i32 [<=640]             @ 266,802,688
//   sRowPtr  i32 [N_USER+1]          @ 268,000,128
//   sBOff    i32 [<=640+1]           @ 268,400,256
//   sBCur    i32 [<=640]             @ 268,402,816
#define SOC_BYTES 12800000
#define FUSED_OFF 25600000
#define IPAIR_OFF 217600000
#define SPAIR_OFF 249600000
#define IRP_OFF   265600000
#define IBOFF_OFF 266800128
#define IBCUR_OFF 266802688
#define SRP_OFF   268000128
#define SBOFF_OFF 268400256
#define SBCUR_OFF 268402816
#define WS_REQUIRED 268802304ull

// ---------------------------------------------------------------------------
__global__ __launch_bounds__(256) void fill_diag(float* __restrict__ o, int n,
                                                 float v) {
  int i = blockIdx.x * blockDim.x + threadIdx.x;
  if (i < n) o[i] = v;
}

__global__ __launch_bounds__(1024) void zero_dual(int* __restrict__ a, int na,
                                                  int* __restrict__ b, int nb) {
  int t = threadIdx.x;
  if (t < na) a[t] = 0;
  if (t < nb) b[t] = 0;
}

// ---------------------------------------------------------------------------
// stage 1: coarse-bucket histogram, both graphs, int4-vectorized row reads.
// blocks [0,512) -> inter; [512,768) -> soc. (nE % 4 == 0 for both.)
// ---------------------------------------------------------------------------
__global__ __launch_bounds__(256) void bucket_hist_dual(
    const int* __restrict__ rowsI, int* __restrict__ bCntI,
    const int* __restrict__ rowsS, int* __restrict__ bCntS) {
  __shared__ int h[NB_MAX];
  const int4* rows4;
  int* bCnt;
  int nQ, nB, b0, nBlk, shift;
  if (blockIdx.x < 512) {
    rows4 = (const int4*)rowsI; bCnt = bCntI; nQ = E_INTER / 4; nB = IB_NB;
    b0 = blockIdx.x; nBlk = 512; shift = ISHIFT;
  } else {
    rows4 = (const int4*)rowsS; bCnt = bCntS; nQ = E_SOC / 4; nB = SB_NB;
    b0 = blockIdx.x - 512; nBlk = 256; shift = SSHIFT;
  }
  for (int i = threadIdx.x; i < nB; i += 256) h[i] = 0;
  __syncthreads();
  int stride = nBlk * 256;
  for (int q = b0 * 256 + threadIdx.x; q < nQ; q += stride) {
    int4 r = rows4[q];
    atomicAdd(&h[r.x >> shift], 1);
    atomicAdd(&h[r.y >> shift], 1);
    atomicAdd(&h[r.z >> shift], 1);
    atomicAdd(&h[r.w >> shift], 1);
  }
  __syncthreads();
  for (int i = threadIdx.x; i < nB; i += 256) {
    int v = h[i];
    if (v) atomicAdd(&bCnt[i], v);
  }
}

// 2-block dispatch: exclusive scan over each graph's bucket counts (n<=1024).
__global__ __launch_bounds__(1024) void scan_dual(
    int* __restrict__ cntI, int* __restrict__ bOffI,
    int* __restrict__ cntS, int* __restrict__ bOffS) {
  __shared__ int waveTot[16];
  int* cnt  = blockIdx.x == 0 ? cntI : cntS;
  int* bOff = blockIdx.x == 0 ? bOffI : bOffS;
  int n     = blockIdx.x == 0 ? IB_NB : SB_NB;
  int t = threadIdx.x;
  int lane = t & 63, w = t >> 6;
  int orig = (t < n) ? cnt[t] : 0;
  int v = orig;
  #pragma unroll
  for (int sh = 1; sh < 64; sh <<= 1) {
    int u = __shfl_up(v, sh, 64);
    if (lane >= sh) v += u;
  }
  if (lane == 63) waveTot[w] = v;
  __syncthreads();
  int woff = 0;
  #pragma unroll
  for (int i = 0; i < 16; i++)
    if (i < w) woff += waveTot[i];
  v += woff;
  int excl = v - orig;
  if (t < n) {
    bOff[t] = excl;
    cnt[t] = excl;   // cursor init (cnt aliases bCur)
  }
  if (t == n - 1) bOff[n] = excl + orig;
}

// ---------------------------------------------------------------------------
// stage 2: LDS-staged binning. Per block: hist its 8192 edges, local scan,
// ONE global atomic per (block,bucket), bucket-sort edges in LDS, then copy
// each bucket run out as a dense wave-burst.
// pack: [63:32]=valbits  [31:shift]=col  [shift-1:0]=row&(rows-1)
// ---------------------------------------------------------------------------
__global__ __launch_bounds__(256) void bin_dual(
    const int* __restrict__ rowsI, const int* __restrict__ colsI,
    const float* __restrict__ valsI, int* __restrict__ gCurI,
    u64* __restrict__ tmpI,
    const int* __restrict__ rowsS, const int* __restrict__ colsS,
    const float* __restrict__ valsS, int* __restrict__ gCurS,
    u64* __restrict__ tmpS) {
  __shared__ int cnt[NB_MAX];
  __shared__ int cur[NB_MAX];
  __shared__ int gB[NB_MAX];
  __shared__ int waveTot[4];
  extern __shared__ u64 ldsE[];        // FCAP = 8192 edges, 64 KB
  const int *rows, *cols;
  const float* vals;
  int* gCur;
  u64* tmp;
  int nE, nB, b0, shift;
  if (blockIdx.x < NBI_CHUNKS) {
    rows = rowsI; cols = colsI; vals = valsI; gCur = gCurI; tmp = tmpI;
    nE = E_INTER; nB = IB_NB; b0 = blockIdx.x; shift = ISHIFT;
  } else {
    rows = rowsS; cols = colsS; vals = valsS; gCur = gCurS; tmp = tmpS;
    nE = E_SOC; nB = SB_NB; b0 = blockIdx.x - NBI_CHUNKS; shift = SSHIFT;
  }
  int t = threadIdx.x;
  int base = b0 * BIN_CHUNK;
  int rmask = (1 << shift) - 1;
  for (int i = t; i < nB; i += 256) cnt[i] = 0;
  __syncthreads();
  // pass 1: histogram (rows only)
  #pragma unroll 4
  for (int i = 0; i < BIN_PER_T; i++) {
    int e = base + t + i * 256;
    if (e < nE) atomicAdd(&cnt[rows[e] >> shift], 1);
  }
  __syncthreads();
  // pass 2: local exclusive scan (3 entries/thread) -> cur
  {
    int i0 = t * 3;
    int c0 = (i0 < nB) ? cnt[i0] : 0;
    int c1 = (i0 + 1 < nB) ? cnt[i0 + 1] : 0;
    int c2 = (i0 + 2 < nB) ? cnt[i0 + 2] : 0;
    int tsum = c0 + c1 + c2;
    int lane = t & 63, w = t >> 6;
    int v = tsum;
    #pragma unroll
    for (int sh = 1; sh < 64; sh <<= 1) {
      int u = __shfl_up(v, sh, 64);
      if (lane >= sh) v += u;
    }
    if (lane == 63) waveTot[w] = v;
    __syncthreads();
    int woff = 0;
    #pragma unroll
    for (int i = 0; i < 4; i++)
      if (i < w) woff += waveTot[i];
    int toff = (v - tsum) + woff;
    if (i0 < nB) cur[i0] = toff;
    if (i0 + 1 < nB) cur[i0 + 1] = toff + c0;
    if (i0 + 2 < nB) cur[i0 + 2] = toff + c0 + c1;
  }
  __syncthreads();
  // global reservation: one atomic per (block,bucket)
  for (int i = t; i < nB; i += 256) {
    int c = cnt[i];
    gB[i] = c ? atomicAdd(&gCur[i], c) : 0;
  }
  __syncthreads();
  // pass 3: scatter edges into LDS bucket-major
  #pragma unroll 4
  for (int i = 0; i < BIN_PER_T; i++) {
    int e = base + t + i * 256;
    if (e < nE) {
      int r = rows[e];
      int p = atomicAdd(&cur[r >> shift], 1);
      ldsE[p] = ((u64)__float_as_uint(vals[e]) << 32) |
                ((u64)(unsigned int)cols[e] << shift) |
                (u64)(r & rmask);
    }
  }
  __syncthreads();
  // pass 4: copy runs out; one wave per bucket, round-robin
  int w = t >> 6, lane = t & 63;
  for (int i = w; i < nB; i += 4) {
    int c = cnt[i];
    if (!c) continue;
    int src = cur[i] - c;   // cur[i] == loff_i + cnt_i now
    int dst = gB[i];
    for (int j = lane; j < c; j += 64) tmp[dst + j] = ldsE[src + j];
  }
}

// ---------------------------------------------------------------------------
// stage 3: one 512-thread block per bucket. Edges kept in LDS (global
// fallback if bucket > FCAP). LDS hist + scan -> rowPtr, then exact CSR
// placement within the bucket's window.
// ---------------------------------------------------------------------------
__global__ __launch_bounds__(512) void finalize_dual(
    const u64* __restrict__ tmpI, const int* __restrict__ bOffI,
    int* __restrict__ rowPtrI, u64* __restrict__ pairsI,
    const u64* __restrict__ tmpS, const int* __restrict__ bOffS,
    int* __restrict__ rowPtrS, u64* __restrict__ pairsS) {
  __shared__ int cur[512];
  __shared__ int waveTot[8];
  extern __shared__ u64 ldsE[];        // FCAP edges
  const u64* tmp;
  const int* bOff;
  int* rowPtr;
  u64* pairs;
  int nRows, nB, b, shift;
  if (blockIdx.x < IB_NB) {
    tmp = tmpI; bOff = bOffI; rowPtr = rowPtrI; pairs = pairsI;
    nRows = N_NODE; nB = IB_NB; b = blockIdx.x; shift = ISHIFT;
  } else {
    tmp = tmpS; bOff = bOffS; rowPtr = rowPtrS; pairs = pairsS;
    nRows = N_USER; nB = SB_NB; b = blockIdx.x - IB_NB; shift = SSHIFT;
  }
  int t = threadIdx.x;
  int rmask = (1 << shift) - 1;
  int start = bOff[b];
  int end = bOff[b + 1];
  int n = end - start;
  bool fits = (n <= FCAP);
  cur[t] = 0;
  __syncthreads();
  if (fits) {
    for (int j = t; j < n; j += 512) {
      u64 pk = tmp[start + j];
      ldsE[j] = pk;
      atomicAdd(&cur[(int)(pk & (u64)rmask)], 1);
    }
  } else {
    for (int j = t; j < n; j += 512)
      atomicAdd(&cur[(int)(tmp[start + j] & (u64)rmask)], 1);
  }
  __syncthreads();
  int orig = cur[t];
  int lane = t & 63, w = t >> 6;
  int v = orig;
  #pragma unroll
  for (int sh = 1; sh < 64; sh <<= 1) {
    int u = __shfl_up(v, sh, 64);
    if (lane >= sh) v += u;
  }
  if (lane == 63) waveTot[w] = v;
  __syncthreads();
  int woff = 0;
  #pragma unroll
  for (int i = 0; i < 8; i++)
    if (i < w) woff += waveTot[i];
  int excl = (v - orig) + woff;
  cur[t] = excl;
  int rowsLoc = 1 << shift;
  int row = (b << shift) + t;
  if (t < rowsLoc && row < nRows) rowPtr[row] = start + excl;
  if (b == 0 && t == 0) rowPtr[nRows] = bOff[nB];
  __syncthreads();
  if (fits) {
    for (int j = t; j < n; j += 512) {
      u64 pk = ldsE[j];
      unsigned int lo = (unsigned int)pk;
      int p = start + atomicAdd(&cur[(int)(lo & (unsigned)rmask)], 1);
      pairs[p] = (pk & 0xffffffff00000000ull) | (lo >> shift);
    }
  } else {
    for (int j = t; j < n; j += 512) {
      u64 pk = tmp[start + j];
      unsigned int lo = (unsigned int)pk;
      int p = start + atomicAdd(&cur[(int)(lo & (unsigned)rmask)], 1);
      pairs[p] = (pk & 0xffffffff00000000ull) | (lo >> shift);
    }
  }
}

// ---------------------------------------------------------------------------
// init: fused[0] = bf16(ini), soc[0] = bf16(uE). float4 loads, packed stores.
// ---------------------------------------------------------------------------
__device__ __forceinline__ unsigned int pack2bf(float a, float b) {
  __hip_bfloat16 ba = __float2bfloat16(a);
  __hip_bfloat16 bb = __float2bfloat16(b);
  unsigned short ua = *(unsigned short*)&ba;
  unsigned short ub = *(unsigned short*)&bb;
  return (unsigned int)ua | ((unsigned int)ub << 16);
}

__global__ __launch_bounds__(256) void init_convert(
    const float* __restrict__ uE, const float* __restrict__ iE,
    __hip_bfloat16* __restrict__ soc, __hip_bfloat16* __restrict__ fused0) {
  int q = blockIdx.x * blockDim.x + threadIdx.x;   // quad index
  if (q >= NODE_ELEMS / 4) return;
  uint2* f4 = (uint2*)fused0;
  if (q < USER_ELEMS / 4) {
    float4 v = ((const float4*)uE)[q];
    uint2 p;
    p.x = pack2bf(v.x, v.y);
    p.y = pack2bf(v.z, v.w);
    ((uint2*)soc)[q] = p;
    f4[q] = p;
  } else {
    float4 v = ((const float4*)iE)[q - USER_ELEMS / 4];
    uint2 p;
    p.x = pack2bf(v.x, v.y);
    p.y = pack2bf(v.z, v.w);
    f4[q] = p;
  }
}

// ---------------------------------------------------------------------------
// pull-SpMM accum helpers: 8-wide batch (scalarized col/val) + tail.
// ---------------------------------------------------------------------------
__device__ __forceinline__ void accum8(
    const u64* __restrict__ pairs, int e, const __hip_bfloat16* __restrict__ x,
    int lane, float& a0, float& a1, float& a2, float& a3) {
  u64 pk[8];
  #pragma unroll
  for (int i = 0; i < 8; i++) pk[i] = pairs[e + i];
  float xv[8], vv[8];
  #pragma unroll
  for (int i = 0; i < 8; i++) {
    int c = __builtin_amdgcn_readfirstlane((int)(unsigned int)pk[i]);
    vv[i] = __uint_as_float(
        __builtin_amdgcn_readfirstlane((unsigned int)(pk[i] >> 32)));
    xv[i] = __bfloat162float(x[c * LATDIM + lane]);
  }
  a0 += vv[0] * xv[0];
  a1 += vv[1] * xv[1];
  a2 += vv[2] * xv[2];
  a3 += vv[3] * xv[3];
  a0 += vv[4] * xv[4];
  a1 += vv[5] * xv[5];
  a2 += vv[6] * xv[6];
  a3 += vv[7] * xv[7];
}

__device__ __forceinline__ void accum_tail(
    const u64* __restrict__ pairs, int e, int end,
    const __hip_bfloat16* __restrict__ x, int lane,
    float& a0, float& a1, float& a2, float& a3) {
  int rem = end - e;
  if (rem & 4) {
    u64 pk[4];
    #pragma unroll
    for (int i = 0; i < 4; i++) pk[i] = pairs[e + i];
    float xv[4], vv[4];
    #pragma unroll
    for (int i = 0; i < 4; i++) {
      int c = __builtin_amdgcn_readfirstlane((int)(unsigned int)pk[i]);
      vv[i] = __uint_as_float(
          __builtin_amdgcn_readfirstlane((unsigned int)(pk[i] >> 32)));
      xv[i] = __bfloat162float(x[c * LATDIM + lane]);
    }
    a0 += vv[0] * xv[0];
    a1 += vv[1] * xv[1];
    a2 += vv[2] * xv[2];
    a3 += vv[3] * xv[3];
    e += 4;
  }
  if (e < end) {                      // 1..3 remain
    int last = end - 1;
    u64 pk[4];
    unsigned int vb[4];
    #pragma unroll
    for (int i = 0; i < 4; i++) {
      int ei = e + i;
      int ec = ei < last ? ei : last;          // wave-uniform select
      pk[i] = pairs[ec];
      vb[i] = (ei < end) ? (unsigned int)(pk[i] >> 32) : 0u;
    }
    float xv[4], vv[4];
    #pragma unroll
    for (int i = 0; i < 4; i++) {
      int c = __builtin_amdgcn_readfirstlane((int)(unsigned int)pk[i]);
      vv[i] = __uint_as_float(__builtin_amdgcn_readfirstlane(vb[i]));
      xv[i] = __bfloat162float(x[c * LATDIM + lane]);
    }
    a0 += vv[0] * xv[0];
    a1 += vv[1] * xv[1];
    a2 += vv[2] * xv[2];
    a3 += vv[3] * xv[3];
  }
}

// shared gate: returns the fused embedding value for a user row
__device__ __forceinline__ float gate_mix(float z, float hi, int lane,
                                          const float* __restrict__ W_gate,
                                          const float* __restrict__ b_gate,
                                          int kNext) {
  const float* wg = W_gate + kNext * 256;
  float p0 = z * wg[lane] + hi * wg[64 + lane];
  float p1 = z * wg[128 + lane] + hi * wg[192 + lane];
  #pragma unroll
  for (int s = 32; s > 0; s >>= 1) {
    p0 += __shfl_xor(p0, s, 64);
    p1 += __shfl_xor(p1, s, 64);
  }
  p0 += b_gate[kNext * 2 + 0];
  p1 += b_gate[kNext * 2 + 1];
  p0 = p0 >= 0.f ? p0 : 0.01f * p0;   // leaky_relu(0.01)
  p1 = p1 >= 0.f ? p1 : 0.01f * p1;
  float mx = fmaxf(p0, p1);
  float e0 = __expf(p0 - mx);
  float e1 = __expf(p1 - mx);
  float inv = 1.f / (e0 + e1);
  return z * (e0 * inv) + hi * (e1 * inv);
}

// ---------------------------------------------------------------------------
// fused SpMM + gate (layers 1..3). User rows interleave the two independent
// gather streams 8+8-wide; item rows: inter only.
// ---------------------------------------------------------------------------
__global__ __launch_bounds__(256) void spmm_fuse(
    const int* __restrict__ iRowPtr, const u64* __restrict__ iPairs,
    const __hip_bfloat16* __restrict__ xI,
    __hip_bfloat16* __restrict__ fusedNext,
    const int* __restrict__ sRowPtr, const u64* __restrict__ sPairs,
    const __hip_bfloat16* __restrict__ socCur,
    __hip_bfloat16* __restrict__ socNxt,
    const float* __restrict__ W_gate,   // (5,2,128)
    const float* __restrict__ b_gate,   // (5,2)
    int kNext) {
  int g = blockIdx.x * 256 + threadIdx.x;
  int row = __builtin_amdgcn_readfirstlane(g >> 6);
  int lane = g & 63;
  if (row >= N_NODE) return;
  int off = row * LATDIM + lane;
  int iS = iRowPtr[row], iE = iRowPtr[row + 1];
  float a0 = 0.f, a1 = 0.f, a2 = 0.f, a3 = 0.f;
  if (row < N_USER) {
    int sS = sRowPtr[row], sE = sRowPtr[row + 1];
    float b0 = 0.f, b1 = 0.f, b2 = 0.f, b3 = 0.f;
    while (iS + 8 <= iE && sS + 8 <= sE) {
      accum8(iPairs, iS, xI, lane, a0, a1, a2, a3);
      accum8(sPairs, sS, socCur, lane, b0, b1, b2, b3);
      iS += 8;
      sS += 8;
    }
    for (; iS + 8 <= iE; iS += 8) accum8(iPairs, iS, xI, lane, a0, a1, a2, a3);
    accum_tail(iPairs, iS, iE, xI, lane, a0, a1, a2, a3);
    for (; sS + 8 <= sE; sS += 8)
      accum8(sPairs, sS, socCur, lane, b0, b1, b2, b3);
    accum_tail(sPairs, sS, sE, socCur, lane, b0, b1, b2, b3);
    float hi = (a0 + a1) + (a2 + a3);
    float z = (b0 + b1) + (b2 + b3);
    socNxt[off] = __float2bfloat16(z);
    fusedNext[off] =
        __float2bfloat16(gate_mix(z, hi, lane, W_gate, b_gate, kNext));
  } else {
    for (; iS + 8 <= iE; iS += 8) accum8(iPairs, iS, xI, lane, a0, a1, a2, a3);
    accum_tail(iPairs, iS, iE, xI, lane, a0, a1, a2, a3);
    fusedNext[off] = __float2bfloat16((a0 + a1) + (a2 + a3));
  }
}

// ---------------------------------------------------------------------------
// last layer: SpMM + gate + 5-way attention, fused. f[4] stays in registers
// (f32, unrounded); f[0..3] are coalesced bf16 row-loads. Writes out (f32)
// directly -- fused[4], soc[4], and the whole final pass are eliminated.
// ---------------------------------------------------------------------------
__global__ __launch_bounds__(256) void spmm_fuse_final(
    const int* __restrict__ iRowPtr, const u64* __restrict__ iPairs,
    const __hip_bfloat16* __restrict__ fusedBase,   // layers 0..3 (xI = +3)
    const int* __restrict__ sRowPtr, const u64* __restrict__ sPairs,
    const __hip_bfloat16* __restrict__ socCur,
    const float* __restrict__ W_gate, const float* __restrict__ b_gate,
    const float* __restrict__ WL1, const float* __restrict__ bL1,
    const float* __restrict__ WL2, const float* __restrict__ bL2,
    float* __restrict__ out) {
  int g = blockIdx.x * 256 + threadIdx.x;
  int row = __builtin_amdgcn_readfirstlane(g >> 6);
  int lane = g & 63;
  if (row >= N_NODE) return;
  int off = row * LATDIM + lane;
  const __hip_bfloat16* xI = fusedBase + (size_t)3 * NODE_ELEMS;
  int iS = iRowPtr[row], iE = iRowPtr[row + 1];
  float a0 = 0.f, a1 = 0.f, a2 = 0.f, a3 = 0.f;
  float f4;
  if (row < N_USER) {
    int sS = sRowPtr[row], sE = sRowPtr[row + 1];
    float b0 = 0.f, b1 = 0.f, b2 = 0.f, b3 = 0.f;
    while (iS + 8 <= iE && sS + 8 <= sE) {
      accum8(iPairs, iS, xI, lane, a0, a1, a2, a3);
      accum8(sPairs, sS, socCur, lane, b0, b1, b2, b3);
      iS += 8;
      sS += 8;
    }
    for (; iS + 8 <= iE; iS += 8) accum8(iPairs, iS, xI, lane, a0, a1, a2, a3);
    accum_tail(iPairs, iS, iE, xI, lane, a0, a1, a2, a3);
    for (; sS + 8 <= sE; sS += 8)
      accum8(sPairs, sS, socCur, lane, b0, b1, b2, b3);
    accum_tail(sPairs, sS, sE, socCur, lane, b0, b1, b2, b3);
    float hi = (a0 + a1) + (a2 + a3);
    float z = (b0 + b1) + (b2 + b3);
    f4 = gate_mix(z, hi, lane, W_gate, b_gate, 4);
  } else {
    for (; iS + 8 <= iE; iS += 8) accum8(iPairs, iS, xI, lane, a0, a1, a2, a3);
    accum_tail(iPairs, iS, iE, xI, lane, a0, a1, a2, a3);
    f4 = (a0 + a1) + (a2 + a3);
  }

  // ---- fused 5-way attention epilogue ----
  float f[5];
  f[4] = f4;
  #pragma unroll
  for (int k = 0; k < 4; k++)
    f[k] =
        __bfloat162float(fusedBase[(size_t)k * NODE_ELEMS + off]);
  const float* WL = (row < N_USER) ? WL1 : WL2;
  const float* bL = (row < N_USER) ? bL1 : bL2;
  float p[5];
  #pragma unroll
  for (int j = 0; j < 5; j++) {
    float s = 0.f;
    #pragma unroll
    for (int k = 0; k < 5; k++) s += f[k] * WL[j * 320 + k * 64 + lane];
    p[j] = s;
  }
  #pragma unroll
  for (int s = 32; s > 0; s >>= 1) {
    #pragma unroll
    for (int j = 0; j < 5; j++) p[j] += __shfl_xor(p[j], s, 64);
  }
  float mx = -1e30f;
  #pragma unroll
  for (int j = 0; j < 5; j++) {
    p[j] += bL[j];
    p[j] = p[j] >= 0.f ? p[j] : 0.01f * p[j];
    mx = fmaxf(mx, p[j]);
  }
  float sum = 0.f;
  #pragma unroll
  for (int j = 0; j < 5; j++) {
    p[j] = __expf(p[j] - mx);
    sum += p[j];
  }
  float inv = 1.f / sum;
  float o = 0.f;
  #pragma unroll
  for (int j = 0; j < 5; j++) o += (p[j] * inv) * f[j];
  out[off] = o;
}

// ---------------------------------------------------------------------------
extern "C" void kernel_launch(void* const* d_in, const int* in_sizes, int n_in,
                              void* d_out, int out_size, void* d_ws,
                              size_t ws_size, hipStream_t stream) {
  const float* uE     = (const float*)d_in[0];
  const float* iE     = (const float*)d_in[1];
  const float* W_gate = (const float*)d_in[2];
  const float* b_gate = (const float*)d_in[3];
  const float* WL1    = (const float*)d_in[4];
  const float* bL1    = (const float*)d_in[5];
  const float* WL2    = (const float*)d_in[6];
  const float* bL2    = (const float*)d_in[7];
  const int* inter_rows = (const int*)d_in[8];
  const int* inter_cols = (const int*)d_in[9];
  const float* inter_vals = (const float*)d_in[10];
  const int* soc_rows   = (const int*)d_in[11];
  const int* soc_cols   = (const int*)d_in[12];
  const float* soc_vals = (const float*)d_in[13];
  float* out = (float*)d_out;

  if (ws_size < WS_REQUIRED) {
    float v = (float)(ws_size / (1024ull * 1024ull));
    fill_diag<<<(out_size + 255) / 256, 256, 0, stream>>>(out, out_size, v);
    return;
  }

  char* ws = (char*)d_ws;
  __hip_bfloat16* socBuf[2] = {(__hip_bfloat16*)ws,
                               (__hip_bfloat16*)(ws + SOC_BYTES)};
  __hip_bfloat16* fused = (__hip_bfloat16*)(ws + FUSED_OFF);
  u64* tmpI = (u64*)(ws + FUSED_OFF);
  u64* tmpS = (u64*)(ws + FUSED_OFF + 32000000);
  u64* iPairs = (u64*)(ws + IPAIR_OFF);
  u64* sPairs = (u64*)(ws + SPAIR_OFF);
  int* iRowPtr = (int*)(ws + IRP_OFF);
  int* iBOff   = (int*)(ws + IBOFF_OFF);
  int* iBCur   = (int*)(ws + IBCUR_OFF);
  int* sRowPtr = (int*)(ws + SRP_OFF);
  int* sBOff   = (int*)(ws + SBOFF_OFF);
  int* sBCur   = (int*)(ws + SBCUR_OFF);

  // ---- CSR build ----
  zero_dual<<<1, 1024, 0, stream>>>(iBCur, IB_NB, sBCur, SB_NB);
  bucket_hist_dual<<<768, 256, 0, stream>>>(inter_rows, iBCur, soc_rows, sBCur);
  scan_dual<<<2, 1024, 0, stream>>>(iBCur, iBOff, sBCur, sBOff);
  bin_dual<<<NBI_CHUNKS + NBS_CHUNKS, 256, FCAP * 8, stream>>>(
      inter_rows, inter_cols, inter_vals, iBCur, tmpI,
      soc_rows, soc_cols, soc_vals, sBCur, tmpS);
  finalize_dual<<<IB_NB + SB_NB, 512, FCAP * 8, stream>>>(
      tmpI, iBOff, iRowPtr, iPairs, tmpS, sBOff, sRowPtr, sPairs);

  // ---- main pipeline ----
  init_convert<<<NODE_ELEMS / 4 / 256, 256, 0, stream>>>(uE, iE, socBuf[0],
                                                         fused);

  for (int k = 0; k < 3; k++) {
    __hip_bfloat16* fk = fused + (size_t)k * NODE_ELEMS;
    spmm_fuse<<<NODE_ELEMS / 256, 256, 0, stream>>>(
        iRowPtr, iPairs, fk, fk + NODE_ELEMS,
        sRowPtr, sPairs, socBuf[k & 1], socBuf[(k + 1) & 1],
        W_gate, b_gate, k + 1);
  }

  spmm_fuse_final<<<NODE_ELEMS / 256, 256, 0, stream>>>(
      iRowPtr, iPairs, fused, sRowPtr, sPairs, socBuf[1],
      W_gate, b_gate, WL1, bL1, WL2, bL2, out);
}